// Round 10
// baseline (586.367 us; speedup 1.0000x reference)
//
#include <hip/hip_runtime.h>
#include <hip/hip_bf16.h>
#include <math.h>

#define D_IN   256
#define D_OUT  128
#define DZ     384   // [low | high | mlp] bf16, 768 B per row
#define NHB    256   // coarse-sort blocks (hist + scatter replay partition)

typedef __attribute__((ext_vector_type(8))) short short8;
typedef __attribute__((ext_vector_type(4))) float floatx4;

__device__ __forceinline__ unsigned short f2bf(float f) {
  union { float f; unsigned u; } v; v.f = f;
  unsigned r = v.u + 0x7fffu + ((v.u >> 16) & 1u);  // RNE
  return (unsigned short)(r >> 16);
}

// ---------------------------------------------------------------------------
// FUSED coarse-histogram + prep. Three block roles:
//   bid < NHB          : LDS histogram of dst>>7 over this block's edge chunk
//                        -> bh[bucket*NHB + bid]   (no global atomics)
//   NHB..NHB+383       : repack [Wl|Wh|Wm] into MFMA B-fragment order
//   rest               : xcvt x fp32 -> bf16, 8 elems/thread
// ---------------------------------------------------------------------------
__global__ __launch_bounds__(256) void hist_prep_kernel(
    const float* __restrict__ Wl, const float* __restrict__ Wh,
    const float* __restrict__ Wm, unsigned short* __restrict__ Bpack,
    const float* __restrict__ x, unsigned short* __restrict__ xb, int n8,
    const int* __restrict__ dst, int* __restrict__ bh, int E, int NB1) {
  __shared__ int hist[1024];  // NB1 <= 1024 (N <= 131072)
  const int bid = blockIdx.x;
  const int t = threadIdx.x;
  if (bid < NHB) {
    for (int k = t; k < NB1; k += 256) hist[k] = 0;
    __syncthreads();
    const int chunk = (E + NHB - 1) / NHB;
    const int base = bid * chunk;
    const int lim = min(E, base + chunk);
    for (int e = base + t; e < lim; e += 256) atomicAdd(&hist[dst[e] >> 7], 1);
    __syncthreads();
    for (int k = t; k < NB1; k += 256) bh[k * NHB + bid] = hist[k];
  } else if (bid < NHB + 384) {
    // repack: frag f = kt*24+nt holds B[k=kt*32+quad*8+j][n=nt*16+(lane&15)]
    int tt = (bid - NHB) * 256 + t;  // 0..98303
    int j = tt & 7;
    int lane = (tt >> 3) & 63;
    int f = tt >> 9;  // 0..191
    int nt = f % 24, kt = f / 24;
    int k = kt * 32 + (lane >> 4) * 8 + j;
    int n_ = nt * 16 + (lane & 15);
    const float* W = (n_ < 128) ? Wl : (n_ < 256 ? Wh : Wm);
    Bpack[tt] = f2bf(W[k * D_OUT + (n_ & 127)]);
  } else {
    int i = (bid - NHB - 384) * 256 + t;
    if (i < n8) {
      const float4* p = (const float4*)x + (size_t)i * 2;
      float4 f0 = p[0], f1 = p[1];
      short8 o;
      o[0] = (short)f2bf(f0.x); o[1] = (short)f2bf(f0.y);
      o[2] = (short)f2bf(f0.z); o[3] = (short)f2bf(f0.w);
      o[4] = (short)f2bf(f1.x); o[5] = (short)f2bf(f1.y);
      o[6] = (short)f2bf(f1.z); o[7] = (short)f2bf(f1.w);
      ((short8*)xb)[i] = o;
    }
  }
}

// ---------------------------------------------------------------------------
// Exclusive scan over M = NB1*NHB ints. scan1 -> per-1024-chunk exclusive +
// chunk totals; scan2 -> exclusive scan of totals. Consumers read
// bhscan[i] + bsum[i>>10] directly (scan3 folded away).
// ---------------------------------------------------------------------------
__global__ __launch_bounds__(256) void scan1_kernel(
    const int* __restrict__ cnt, int* __restrict__ outp,
    int* __restrict__ bsum, int n) {
  __shared__ int sd[256];
  int t = threadIdx.x;
  int base = blockIdx.x * 1024 + t * 4;
  int v0 = base + 0 < n ? cnt[base + 0] : 0;
  int v1 = base + 1 < n ? cnt[base + 1] : 0;
  int v2 = base + 2 < n ? cnt[base + 2] : 0;
  int v3 = base + 3 < n ? cnt[base + 3] : 0;
  int tsum = v0 + v1 + v2 + v3;
  sd[t] = tsum;
  __syncthreads();
  for (int off = 1; off < 256; off <<= 1) {
    int add = (t >= off) ? sd[t - off] : 0;
    __syncthreads();
    sd[t] += add;
    __syncthreads();
  }
  int excl = sd[t] - tsum;
  if (base + 0 < n) outp[base + 0] = excl;
  if (base + 1 < n) outp[base + 1] = excl + v0;
  if (base + 2 < n) outp[base + 2] = excl + v0 + v1;
  if (base + 3 < n) outp[base + 3] = excl + v0 + v1 + v2;
  if (t == 255) bsum[blockIdx.x] = sd[255];
}

__global__ __launch_bounds__(256) void scan2_kernel(int* __restrict__ bsum,
                                                    int nb) {
  __shared__ int sd[256];
  int t = threadIdx.x;
  int v = t < nb ? bsum[t] : 0;
  sd[t] = v;
  __syncthreads();
  for (int off = 1; off < 256; off <<= 1) {
    int add = (t >= off) ? sd[t - off] : 0;
    __syncthreads();
    sd[t] += add;
    __syncthreads();
  }
  if (t < nb) bsum[t] = sd[t] - v;  // exclusive
}

// ---------------------------------------------------------------------------
// FUSED gemm + coarse scatter (even/odd role split, r6's proven pattern).
//   even ids < 2*NHB : replay edge chunk rb=bid>>1; positions from per-bucket
//                      LDS cursors seeded with bhscan[k*NHB+rb]+bsum fold
//                      -> tmp[pos] = {src | dlow7<<20, bf16(wl)|bf16(wh)<<16}
//   odd / remainder  : gemm tiles (round-0 math/layout)
// gemm occupancy fix: epilogue LDS tile halved to 32 rows (25 KB, two passes)
// + launch_bounds(512,8) -> 4 blocks/CU = 32 waves (was 2 blocks/16 waves).
// r1 profile showed gemm latency-bound at Occupancy 36% / MfmaUtil 5.5%;
// doubling resident waves attacks exactly that.
// ---------------------------------------------------------------------------
#define LDSROW 392  // shorts/row: 784 B (16B-aligned)
__global__ __launch_bounds__(512, 8) void gemm_sort_kernel(
    const unsigned short* __restrict__ xb,
    const unsigned short* __restrict__ Bpack, unsigned short* __restrict__ Z,
    int n_nodes, const int* __restrict__ src, const int* __restrict__ dst,
    const float* __restrict__ wlo, const float* __restrict__ whi,
    const int* __restrict__ bhscan, const int* __restrict__ bsum,
    uint2* __restrict__ tmp, int E, int NB1) {
  __shared__ unsigned short tile[32 * LDSROW];  // 25088 B
  const int bid = blockIdx.x;

  int gemm_id;
  if (bid < 2 * NHB) {
    if ((bid & 1) == 0) {  // ---- coarse scatter block ----
      int rb = bid >> 1;
      int* cur = (int*)tile;
      int t = threadIdx.x;
      for (int k = t; k < NB1; k += 512) {
        int idx = k * NHB + rb;
        cur[k] = bhscan[idx] + bsum[idx >> 10];
      }
      __syncthreads();
      const int chunk = (E + NHB - 1) / NHB;
      const int base = rb * chunk;
      const int lim = min(E, base + chunk);
      for (int e = base + t; e < lim; e += 512) {
        int d = dst[e];
        int pos = atomicAdd(&cur[d >> 7], 1);  // LDS atomic
        unsigned wl = f2bf(wlo[e]), wh = f2bf(whi[e]);
        tmp[pos] = make_uint2((unsigned)src[e] | ((unsigned)(d & 127) << 20),
                              wl | (wh << 16));
      }
      return;
    }
    gemm_id = bid >> 1;
  } else {
    gemm_id = bid - 2 * NHB + NHB;
  }

  // ---- gemm block ----
  const int lane = threadIdx.x & 63;
  const int w = threadIdx.x >> 6;  // 0..7: column group (3 ctiles)
  const int rowbase = gemm_id * 64;
  const int m16 = lane & 15, quad = lane >> 4;

  floatx4 acc[4][3];
#pragma unroll
  for (int s = 0; s < 4; s++)
#pragma unroll
    for (int c = 0; c < 3; c++) acc[s][c] = (floatx4)(0.f);

  const short8* xr[4];
#pragma unroll
  for (int s = 0; s < 4; s++) {
    int r = rowbase + s * 16 + m16;
    if (r > n_nodes - 1) r = n_nodes - 1;  // clamp; stores are guarded
    xr[s] = (const short8*)xb + (size_t)r * 32 + quad;  // row*256/8 + quad
  }
  const short8* bp = (const short8*)Bpack + lane;

#pragma unroll
  for (int kt = 0; kt < 8; kt++) {
    short8 a[4];
#pragma unroll
    for (int s = 0; s < 4; s++) a[s] = xr[s][kt * 4];
#pragma unroll
    for (int c = 0; c < 3; c++) {
      short8 b = bp[(kt * 24 + w * 3 + c) * 64];
#pragma unroll
      for (int s = 0; s < 4; s++)
        acc[s][c] =
            __builtin_amdgcn_mfma_f32_16x16x32_bf16(a[s], b, acc[s][c], 0, 0, 0);
    }
  }

  // two-pass LDS epilogue: strips {0,1} then {2,3} through a 32-row tile.
  // C-layout: local row = s*16+quad*4+r, col = (w*3+c)*16+m16.
#pragma unroll
  for (int half = 0; half < 2; half++) {
    if (half) __syncthreads();  // tile reuse: wait for pass-1 stores
#pragma unroll
    for (int s = 0; s < 2; s++)
#pragma unroll
      for (int c = 0; c < 3; c++)
#pragma unroll
        for (int r = 0; r < 4; r++)
          tile[(s * 16 + quad * 4 + r) * LDSROW + (w * 3 + c) * 16 + m16] =
              f2bf(acc[half * 2 + s][c][r]);
    __syncthreads();
    // coalesced store: 32 rows x 48 chunks of 16B = 1536 chunks / 512 thr
#pragma unroll
    for (int it = 0; it < 3; it++) {
      int chunk = it * 512 + threadIdx.x;
      int row = chunk / 48, col = (chunk % 48) * 8;
      int grow = rowbase + half * 32 + row;
      if (grow < n_nodes)
        *(short8*)(Z + (size_t)grow * DZ + col) =
            *(const short8*)&tile[row * LDSROW + col];
    }
  }
}

// ---------------------------------------------------------------------------
// Fine pass: one block per coarse bucket (128 nodes, ~2046 edges).
// LDS 128-bin histogram + LDS scan -> final meta grouped by dst + rowptr.
// All reads/writes are streaming or segment-local (L2-resident).
// ---------------------------------------------------------------------------
__global__ __launch_bounds__(256) void fine_kernel(
    const uint2* __restrict__ tmp, const int* __restrict__ bhscan,
    const int* __restrict__ bsum, uint2* __restrict__ meta,
    int* __restrict__ rowptr, int NB1, int n, int E) {
  __shared__ int fh[128];
  __shared__ int sd[128];
  __shared__ int cur[128];
  const int b = blockIdx.x;
  const int t = threadIdx.x;
  auto scanidx = [&](int i) { return bhscan[i] + bsum[i >> 10]; };
  const int s0 = scanidx(b * NHB);
  const int s1 = (b == NB1 - 1) ? E : scanidx((b + 1) * NHB);

  if (t < 128) fh[t] = 0;
  __syncthreads();
  for (int i = s0 + t; i < s1; i += 256)
    atomicAdd(&fh[(tmp[i].x >> 20) & 127], 1);
  __syncthreads();

  // exclusive scan of the 128 bins
  if (t < 128) sd[t] = fh[t];
  __syncthreads();
  for (int off = 1; off < 128; off <<= 1) {
    int add = (t >= off && t < 128) ? sd[t - off] : 0;
    __syncthreads();
    if (t < 128) sd[t] += add;
    __syncthreads();
  }
  if (t < 128) {
    int excl = sd[t] - fh[t];
    cur[t] = excl;
    int node = b * 128 + t;
    if (node < n) rowptr[node] = s0 + excl;
  }
  if (b == 0 && t == 0) rowptr[n] = E;
  __syncthreads();

  for (int i = s0 + t; i < s1; i += 256) {
    uint2 v = tmp[i];
    int d = (v.x >> 20) & 127;
    int pos = s0 + atomicAdd(&cur[d], 1);  // LDS atomic
    meta[pos] = make_uint2(v.x & 0xFFFFFu, v.y);
  }
}

// ---------------------------------------------------------------------------
// K_node: CSR gather + relu + attention3. 128-thr blocks = 2 independent
// waves = 2 nodes. readfirstlane(node) -> rowptr/meta via scalar loads.
// Lane l<32: low dims 4l..4l+3; l>=32: high dims. One uint2 Z load per edge.
// NEW: depth-2 x width-8 software pipeline (named A/B buffers, static
// indexing per rule #20) -> 16 outstanding gathers/wave. meta indices live
// in SGPRs, z regs +16 stay inside the 64-VGPR quantum -> same occupancy.
// ---------------------------------------------------------------------------
__global__ __launch_bounds__(128) void node_kernel(
    const unsigned short* __restrict__ Zh, const int* __restrict__ rowptr,
    const uint2* __restrict__ meta, const float* __restrict__ a_low,
    const float* __restrict__ a_high, const float* __restrict__ a_mlp,
    const float* __restrict__ att_vec, float* __restrict__ out, int n_nodes) {
  int node = blockIdx.x * 2 + (threadIdx.x >> 6);
  if (node >= n_nodes) return;
  node = __builtin_amdgcn_readfirstlane(node);  // wave-uniform -> s_loads
  const int lane = threadIdx.x & 63;
  const int isHigh = lane >> 5;
  const int dbase = (lane & 31) * 4;
  const char* Zb = (const char*)Zh;

  const int start = rowptr[node];
  const int end = rowptr[node + 1];

  float acc0 = 0.f, acc1 = 0.f, acc2 = 0.f, acc3 = 0.f;
  auto wsel = [&](unsigned p) {
    return __uint_as_float(isHigh ? (p & 0xffff0000u) : (p << 16));
  };
  auto step = [&](uint2 z, float wv) {
    acc0 += wv * __uint_as_float(z.x << 16);
    acc1 += wv * __uint_as_float(z.x & 0xffff0000u);
    acc2 += wv * __uint_as_float(z.y << 16);
    acc3 += wv * __uint_as_float(z.y & 0xffff0000u);
  };

  uint2 mA[8], zA[8], mB[8], zB[8];
  auto loadg = [&](uint2* m, uint2* z, int g) {
    int jj = start + g * 8;
#pragma unroll
    for (int u = 0; u < 8; u++) m[u] = meta[jj + u];
#pragma unroll
    for (int u = 0; u < 8; u++)
      z[u] = *(const uint2*)(Zb + (size_t)m[u].x * 768 + lane * 8);
  };
  auto computeg = [&](const uint2* m, const uint2* z) {
#pragma unroll
    for (int u = 0; u < 8; u++) step(z[u], wsel(m[u].y));
  };

  const int n8cnt = (end - start) >> 3;
  if (n8cnt > 0) loadg(mA, zA, 0);
  if (n8cnt > 1) loadg(mB, zB, 1);
  int g = 0;
  for (; g + 1 < n8cnt; g += 2) {
    computeg(mA, zA);
    if (g + 2 < n8cnt) loadg(mA, zA, g + 2);
    computeg(mB, zB);
    if (g + 3 < n8cnt) loadg(mB, zB, g + 3);
  }
  if (g < n8cnt) computeg(mA, zA);
  for (int j = start + n8cnt * 8; j < end; j++) {
    uint2 m0 = meta[j];
    uint2 z0 = *(const uint2*)(Zb + (size_t)m0.x * 768 + lane * 8);
    step(z0, wsel(m0.y));
  }

  float h0 = fmaxf(acc0, 0.f), h1 = fmaxf(acc1, 0.f);
  float h2 = fmaxf(acc2, 0.f), h3 = fmaxf(acc3, 0.f);

  uint2 zm =
      *(const uint2*)(Zb + (size_t)node * 768 + 512 + (size_t)(lane & 31) * 8);
  float q0 = fmaxf(__uint_as_float(zm.x << 16), 0.f);
  float q1 = fmaxf(__uint_as_float(zm.x & 0xffff0000u), 0.f);
  float q2 = fmaxf(__uint_as_float(zm.y << 16), 0.f);
  float q3 = fmaxf(__uint_as_float(zm.y & 0xffff0000u), 0.f);

  const float* av_b = isHigh ? a_high : a_low;
  float4 ab = *(const float4*)&av_b[dbase];
  float4 am = *(const float4*)&a_mlp[dbase];
  float v1 = h0 * ab.x + h1 * ab.y + h2 * ab.z + h3 * ab.w;
  float v2 = isHigh ? 0.f : (q0 * am.x + q1 * am.y + q2 * am.z + q3 * am.w);
#pragma unroll
  for (int off = 1; off < 32; off <<= 1) {
    v1 += __shfl_xor(v1, off);
    v2 += __shfl_xor(v2, off);
  }
  float s_lo = __shfl(v1, 0);
  float s_hi = __shfl(v1, 32);
  float s_ml = __shfl(v2, 0);

  float g0 = 1.f / (1.f + __expf(-s_lo));
  float g1 = 1.f / (1.f + __expf(-s_hi));
  float g2 = 1.f / (1.f + __expf(-s_ml));
  const float inv3 = 1.f / 3.f;
  float m0 = (g0 * att_vec[0] + g1 * att_vec[3] + g2 * att_vec[6]) * inv3;
  float m1 = (g0 * att_vec[1] + g1 * att_vec[4] + g2 * att_vec[7]) * inv3;
  float m2 = (g0 * att_vec[2] + g1 * att_vec[5] + g2 * att_vec[8]) * inv3;
  float mx = fmaxf(m0, fmaxf(m1, m2));
  float e0 = __expf(m0 - mx), e1 = __expf(m1 - mx), e2 = __expf(m2 - mx);
  float inv = 1.f / (e0 + e1 + e2);
  float c0 = 3.f * inv * e0, c1 = 3.f * inv * e1, c2 = 3.f * inv * e2;

  float hh0 = __shfl_xor(h0, 32);
  float hh1 = __shfl_xor(h1, 32);
  float hh2 = __shfl_xor(h2, 32);
  float hh3 = __shfl_xor(h3, 32);

  if (!isHigh) {
    float4 o;
    o.x = c0 * h0 + c1 * hh0 + c2 * q0;
    o.y = c0 * h1 + c1 * hh1 + c2 * q1;
    o.z = c0 * h2 + c1 * hh2 + c2 * q2;
    o.w = c0 * h3 + c1 * hh3 + c2 * q3;
    *(float4*)&out[(size_t)node * D_OUT + dbase] = o;
  }
}

// ---------------------------------------------------------------------------
extern "C" void kernel_launch(void* const* d_in, const int* in_sizes, int n_in,
                              void* d_out, int out_size, void* d_ws,
                              size_t ws_size, hipStream_t stream) {
  const float* x    = (const float*)d_in[0];
  const int*   esrc = (const int*)d_in[1];
  const int*   edst = (const int*)d_in[2];
  const float* wlo  = (const float*)d_in[3];
  const float* whi  = (const float*)d_in[4];
  const float* Wl   = (const float*)d_in[6];
  const float* Wh   = (const float*)d_in[7];
  const float* Wm   = (const float*)d_in[8];
  const float* alo  = (const float*)d_in[9];
  const float* ahi  = (const float*)d_in[10];
  const float* amlp = (const float*)d_in[11];
  const float* av   = (const float*)d_in[12];
  float* out = (float*)d_out;

  const int N = in_sizes[0] / D_IN;  // 100000
  const int E = in_sizes[1];         // 1600000
  const int NB1 = (N + 127) >> 7;    // coarse buckets (782)
  const int M = NB1 * NHB;           // bh entries (200192)

  char* ws = (char*)d_ws;
  size_t off = 0;
  auto carve = [&](size_t bytes) -> void* {
    void* p = ws + off;
    off = (off + bytes + 255) & ~(size_t)255;
    return p;
  };
  unsigned short* Z      = (unsigned short*)carve((size_t)N * DZ * 2);
  unsigned short* xb     = (unsigned short*)carve((size_t)N * D_IN * 2);
  unsigned short* Bpack  = (unsigned short*)carve(98304 * 2);
  int*   bh     = (int*)carve((size_t)M * 4);
  int*   bhscan = (int*)carve((size_t)M * 4);
  int*   bsum   = (int*)carve(256 * 4);
  int*   rowptr = (int*)carve((size_t)(N + 1) * 4);
  uint2* tmp    = (uint2*)carve((size_t)E * 8);
  uint2* meta   = (uint2*)carve((size_t)E * 8);

  int n8 = in_sizes[0] / 8;
  int nxb = (n8 + 255) / 256;

  // coarse histogram + prep (fused roles)
  hist_prep_kernel<<<NHB + 384 + nxb, 256, 0, stream>>>(Wl, Wh, Wm, Bpack, x,
                                                        xb, n8, edst, bh, E,
                                                        NB1);
  // exclusive scan of bh (scan3 folded into consumers)
  int nb1s = (M + 1023) / 1024;
  scan1_kernel<<<nb1s, 256, 0, stream>>>(bh, bhscan, bsum, M);
  scan2_kernel<<<1, 256, 0, stream>>>(bsum, nb1s);

  // fused gemm + coarse scatter (no global atomics)
  int ngemm = (N + 63) / 64;
  gemm_sort_kernel<<<ngemm + NHB, 512, 0, stream>>>(
      xb, Bpack, Z, N, esrc, edst, wlo, whi, bhscan, bsum, tmp, E, NB1);

  // fine sort within buckets -> meta + rowptr
  fine_kernel<<<NB1, 256, 0, stream>>>(tmp, bhscan, bsum, meta, rowptr, NB1, N,
                                       E);

  node_kernel<<<(N + 1) / 2, 128, 0, stream>>>(Z, rowptr, meta, alo, ahi, amlp,
                                               av, out, N);
}

// Round 11
// 450.859 us; speedup vs baseline: 1.3006x; 1.3006x over previous
//
#include <hip/hip_runtime.h>
#include <hip/hip_bf16.h>
#include <math.h>

#define D_IN   256
#define D_OUT  128
#define DZ     384   // [low | high | mlp] bf16, 768 B per row
#define NHB    256   // coarse-sort blocks (hist + scatter replay partition)

typedef __attribute__((ext_vector_type(8))) short short8;
typedef __attribute__((ext_vector_type(4))) float floatx4;

__device__ __forceinline__ unsigned short f2bf(float f) {
  union { float f; unsigned u; } v; v.f = f;
  unsigned r = v.u + 0x7fffu + ((v.u >> 16) & 1u);  // RNE
  return (unsigned short)(r >> 16);
}

// ---------------------------------------------------------------------------
// FUSED coarse-histogram + prep. Three block roles:
//   bid < NHB          : LDS histogram of dst>>7 over this block's edge chunk
//                        -> bh[bucket*NHB + bid]   (no global atomics)
//   NHB..NHB+383       : repack [Wl|Wh|Wm] into MFMA B-fragment order
//   rest               : xcvt x fp32 -> bf16, 8 elems/thread
// ---------------------------------------------------------------------------
__global__ __launch_bounds__(256) void hist_prep_kernel(
    const float* __restrict__ Wl, const float* __restrict__ Wh,
    const float* __restrict__ Wm, unsigned short* __restrict__ Bpack,
    const float* __restrict__ x, unsigned short* __restrict__ xb, int n8,
    const int* __restrict__ dst, int* __restrict__ bh, int E, int NB1) {
  __shared__ int hist[1024];  // NB1 <= 1024 (N <= 131072)
  const int bid = blockIdx.x;
  const int t = threadIdx.x;
  if (bid < NHB) {
    for (int k = t; k < NB1; k += 256) hist[k] = 0;
    __syncthreads();
    const int chunk = (E + NHB - 1) / NHB;
    const int base = bid * chunk;
    const int lim = min(E, base + chunk);
    for (int e = base + t; e < lim; e += 256) atomicAdd(&hist[dst[e] >> 7], 1);
    __syncthreads();
    for (int k = t; k < NB1; k += 256) bh[k * NHB + bid] = hist[k];
  } else if (bid < NHB + 384) {
    // repack: frag f = kt*24+nt holds B[k=kt*32+quad*8+j][n=nt*16+(lane&15)]
    int tt = (bid - NHB) * 256 + t;  // 0..98303
    int j = tt & 7;
    int lane = (tt >> 3) & 63;
    int f = tt >> 9;  // 0..191
    int nt = f % 24, kt = f / 24;
    int k = kt * 32 + (lane >> 4) * 8 + j;
    int n_ = nt * 16 + (lane & 15);
    const float* W = (n_ < 128) ? Wl : (n_ < 256 ? Wh : Wm);
    Bpack[tt] = f2bf(W[k * D_OUT + (n_ & 127)]);
  } else {
    int i = (bid - NHB - 384) * 256 + t;
    if (i < n8) {
      const float4* p = (const float4*)x + (size_t)i * 2;
      float4 f0 = p[0], f1 = p[1];
      short8 o;
      o[0] = (short)f2bf(f0.x); o[1] = (short)f2bf(f0.y);
      o[2] = (short)f2bf(f0.z); o[3] = (short)f2bf(f0.w);
      o[4] = (short)f2bf(f1.x); o[5] = (short)f2bf(f1.y);
      o[6] = (short)f2bf(f1.z); o[7] = (short)f2bf(f1.w);
      ((short8*)xb)[i] = o;
    }
  }
}

// ---------------------------------------------------------------------------
// Exclusive scan over M = NB1*NHB ints. scan1 -> per-1024-chunk exclusive +
// chunk totals; scan2 -> exclusive scan of totals. Consumers read
// bhscan[i] + bsum[i>>10] directly (scan3 folded away).
// ---------------------------------------------------------------------------
__global__ __launch_bounds__(256) void scan1_kernel(
    const int* __restrict__ cnt, int* __restrict__ outp,
    int* __restrict__ bsum, int n) {
  __shared__ int sd[256];
  int t = threadIdx.x;
  int base = blockIdx.x * 1024 + t * 4;
  int v0 = base + 0 < n ? cnt[base + 0] : 0;
  int v1 = base + 1 < n ? cnt[base + 1] : 0;
  int v2 = base + 2 < n ? cnt[base + 2] : 0;
  int v3 = base + 3 < n ? cnt[base + 3] : 0;
  int tsum = v0 + v1 + v2 + v3;
  sd[t] = tsum;
  __syncthreads();
  for (int off = 1; off < 256; off <<= 1) {
    int add = (t >= off) ? sd[t - off] : 0;
    __syncthreads();
    sd[t] += add;
    __syncthreads();
  }
  int excl = sd[t] - tsum;
  if (base + 0 < n) outp[base + 0] = excl;
  if (base + 1 < n) outp[base + 1] = excl + v0;
  if (base + 2 < n) outp[base + 2] = excl + v0 + v1;
  if (base + 3 < n) outp[base + 3] = excl + v0 + v1 + v2;
  if (t == 255) bsum[blockIdx.x] = sd[255];
}

__global__ __launch_bounds__(256) void scan2_kernel(int* __restrict__ bsum,
                                                    int nb) {
  __shared__ int sd[256];
  int t = threadIdx.x;
  int v = t < nb ? bsum[t] : 0;
  sd[t] = v;
  __syncthreads();
  for (int off = 1; off < 256; off <<= 1) {
    int add = (t >= off) ? sd[t - off] : 0;
    __syncthreads();
    sd[t] += add;
    __syncthreads();
  }
  if (t < nb) bsum[t] = sd[t] - v;  // exclusive
}

// ---------------------------------------------------------------------------
// FUSED gemm + coarse scatter (even/odd role split, r6's proven pattern).
//   even ids < 2*NHB : replay edge chunk rb=bid>>1; positions from per-bucket
//                      LDS cursors seeded with bhscan[k*NHB+rb]+bsum fold
//                      -> tmp[pos] = {src | dlow7<<20, bf16(wl)|bf16(wh)<<16}
//   odd / remainder  : gemm tiles (round-0 math/layout)
// Occupancy fix v2: 32-row two-pass epilogue (25 KB LDS -> LDS allows 6
// blocks/CU, wave cap 4 blocks = 32 waves/CU) with launch_bounds(512,4)
// (VGPR cap 128 — the 48-VGPR acc stays in registers; r10's (512,8) capped
// at 64 VGPR and spilled acc -> 633 MB scratch writes, 2x regression).
// ---------------------------------------------------------------------------
#define LDSROW 392  // shorts/row: 784 B (16B-aligned)
__global__ __launch_bounds__(512, 4) void gemm_sort_kernel(
    const unsigned short* __restrict__ xb,
    const unsigned short* __restrict__ Bpack, unsigned short* __restrict__ Z,
    int n_nodes, const int* __restrict__ src, const int* __restrict__ dst,
    const float* __restrict__ wlo, const float* __restrict__ whi,
    const int* __restrict__ bhscan, const int* __restrict__ bsum,
    uint2* __restrict__ tmp, int E, int NB1) {
  __shared__ unsigned short tile[32 * LDSROW];  // 25088 B
  const int bid = blockIdx.x;

  int gemm_id;
  if (bid < 2 * NHB) {
    if ((bid & 1) == 0) {  // ---- coarse scatter block ----
      int rb = bid >> 1;
      int* cur = (int*)tile;
      int t = threadIdx.x;
      for (int k = t; k < NB1; k += 512) {
        int idx = k * NHB + rb;
        cur[k] = bhscan[idx] + bsum[idx >> 10];
      }
      __syncthreads();
      const int chunk = (E + NHB - 1) / NHB;
      const int base = rb * chunk;
      const int lim = min(E, base + chunk);
      for (int e = base + t; e < lim; e += 512) {
        int d = dst[e];
        int pos = atomicAdd(&cur[d >> 7], 1);  // LDS atomic
        unsigned wl = f2bf(wlo[e]), wh = f2bf(whi[e]);
        tmp[pos] = make_uint2((unsigned)src[e] | ((unsigned)(d & 127) << 20),
                              wl | (wh << 16));
      }
      return;
    }
    gemm_id = bid >> 1;
  } else {
    gemm_id = bid - 2 * NHB + NHB;
  }

  // ---- gemm block ----
  const int lane = threadIdx.x & 63;
  const int w = threadIdx.x >> 6;  // 0..7: column group (3 ctiles)
  const int rowbase = gemm_id * 64;
  const int m16 = lane & 15, quad = lane >> 4;

  floatx4 acc[4][3];
#pragma unroll
  for (int s = 0; s < 4; s++)
#pragma unroll
    for (int c = 0; c < 3; c++) acc[s][c] = (floatx4)(0.f);

  const short8* xr[4];
#pragma unroll
  for (int s = 0; s < 4; s++) {
    int r = rowbase + s * 16 + m16;
    if (r > n_nodes - 1) r = n_nodes - 1;  // clamp; stores are guarded
    xr[s] = (const short8*)xb + (size_t)r * 32 + quad;  // row*256/8 + quad
  }
  const short8* bp = (const short8*)Bpack + lane;

#pragma unroll
  for (int kt = 0; kt < 8; kt++) {
    short8 a[4];
#pragma unroll
    for (int s = 0; s < 4; s++) a[s] = xr[s][kt * 4];
#pragma unroll
    for (int c = 0; c < 3; c++) {
      short8 b = bp[(kt * 24 + w * 3 + c) * 64];
#pragma unroll
      for (int s = 0; s < 4; s++)
        acc[s][c] =
            __builtin_amdgcn_mfma_f32_16x16x32_bf16(a[s], b, acc[s][c], 0, 0, 0);
    }
  }

  // two-pass LDS epilogue: strips {0,1} then {2,3} through a 32-row tile.
  // C-layout: local row = s*16+quad*4+r, col = (w*3+c)*16+m16.
#pragma unroll
  for (int half = 0; half < 2; half++) {
    if (half) __syncthreads();  // tile reuse: wait for pass-1 loads done
#pragma unroll
    for (int s = 0; s < 2; s++)
#pragma unroll
      for (int c = 0; c < 3; c++)
#pragma unroll
        for (int r = 0; r < 4; r++)
          tile[(s * 16 + quad * 4 + r) * LDSROW + (w * 3 + c) * 16 + m16] =
              f2bf(acc[half * 2 + s][c][r]);
    __syncthreads();
    // coalesced store: 32 rows x 48 chunks of 16B = 1536 chunks / 512 thr
#pragma unroll
    for (int it = 0; it < 3; it++) {
      int chunk = it * 512 + threadIdx.x;
      int row = chunk / 48, col = (chunk % 48) * 8;
      int grow = rowbase + half * 32 + row;
      if (grow < n_nodes)
        *(short8*)(Z + (size_t)grow * DZ + col) =
            *(const short8*)&tile[row * LDSROW + col];
    }
  }
}

// ---------------------------------------------------------------------------
// Fine pass: one block per coarse bucket (128 nodes, ~2046 edges).
// LDS 128-bin histogram + LDS scan -> final meta grouped by dst + rowptr.
// All reads/writes are streaming or segment-local (L2-resident).
// ---------------------------------------------------------------------------
__global__ __launch_bounds__(256) void fine_kernel(
    const uint2* __restrict__ tmp, const int* __restrict__ bhscan,
    const int* __restrict__ bsum, uint2* __restrict__ meta,
    int* __restrict__ rowptr, int NB1, int n, int E) {
  __shared__ int fh[128];
  __shared__ int sd[128];
  __shared__ int cur[128];
  const int b = blockIdx.x;
  const int t = threadIdx.x;
  auto scanidx = [&](int i) { return bhscan[i] + bsum[i >> 10]; };
  const int s0 = scanidx(b * NHB);
  const int s1 = (b == NB1 - 1) ? E : scanidx((b + 1) * NHB);

  if (t < 128) fh[t] = 0;
  __syncthreads();
  for (int i = s0 + t; i < s1; i += 256)
    atomicAdd(&fh[(tmp[i].x >> 20) & 127], 1);
  __syncthreads();

  // exclusive scan of the 128 bins
  if (t < 128) sd[t] = fh[t];
  __syncthreads();
  for (int off = 1; off < 128; off <<= 1) {
    int add = (t >= off && t < 128) ? sd[t - off] : 0;
    __syncthreads();
    if (t < 128) sd[t] += add;
    __syncthreads();
  }
  if (t < 128) {
    int excl = sd[t] - fh[t];
    cur[t] = excl;
    int node = b * 128 + t;
    if (node < n) rowptr[node] = s0 + excl;
  }
  if (b == 0 && t == 0) rowptr[n] = E;
  __syncthreads();

  for (int i = s0 + t; i < s1; i += 256) {
    uint2 v = tmp[i];
    int d = (v.x >> 20) & 127;
    int pos = s0 + atomicAdd(&cur[d], 1);  // LDS atomic
    meta[pos] = make_uint2(v.x & 0xFFFFFu, v.y);
  }
}

// ---------------------------------------------------------------------------
// K_node: CSR gather + relu + attention3. 128-thr blocks = 2 independent
// waves = 2 nodes. readfirstlane(node) -> rowptr/meta via scalar loads.
// Lane l<32: low dims 4l..4l+3; l>=32: high dims. One uint2 Z load per edge,
// unroll x8. (round-0 structure: best measured at ~123-125us, stable across
// three gather variants -> near its L3-path floor)
// ---------------------------------------------------------------------------
__global__ __launch_bounds__(128) void node_kernel(
    const unsigned short* __restrict__ Zh, const int* __restrict__ rowptr,
    const uint2* __restrict__ meta, const float* __restrict__ a_low,
    const float* __restrict__ a_high, const float* __restrict__ a_mlp,
    const float* __restrict__ att_vec, float* __restrict__ out, int n_nodes) {
  int node = blockIdx.x * 2 + (threadIdx.x >> 6);
  if (node >= n_nodes) return;
  node = __builtin_amdgcn_readfirstlane(node);  // wave-uniform -> s_loads
  const int lane = threadIdx.x & 63;
  const int isHigh = lane >> 5;
  const int dbase = (lane & 31) * 4;
  const char* Zb = (const char*)Zh;

  const int start = rowptr[node];
  const int end = rowptr[node + 1];

  float acc0 = 0.f, acc1 = 0.f, acc2 = 0.f, acc3 = 0.f;
  auto wsel = [&](unsigned p) {
    return __uint_as_float(isHigh ? (p & 0xffff0000u) : (p << 16));
  };
  auto step = [&](uint2 z, float wv) {
    acc0 += wv * __uint_as_float(z.x << 16);
    acc1 += wv * __uint_as_float(z.x & 0xffff0000u);
    acc2 += wv * __uint_as_float(z.y << 16);
    acc3 += wv * __uint_as_float(z.y & 0xffff0000u);
  };

  int j = start;
  const int nfull = (end - start) & ~7;
  for (; j < start + nfull; j += 8) {
    uint2 m[8], z[8];
#pragma unroll
    for (int u = 0; u < 8; u++) m[u] = meta[j + u];
#pragma unroll
    for (int u = 0; u < 8; u++)
      z[u] = *(const uint2*)(Zb + (size_t)m[u].x * 768 + lane * 8);
#pragma unroll
    for (int u = 0; u < 8; u++) step(z[u], wsel(m[u].y));
  }
  for (; j < end; j++) {
    uint2 m0 = meta[j];
    uint2 z0 = *(const uint2*)(Zb + (size_t)m0.x * 768 + lane * 8);
    step(z0, wsel(m0.y));
  }

  float h0 = fmaxf(acc0, 0.f), h1 = fmaxf(acc1, 0.f);
  float h2 = fmaxf(acc2, 0.f), h3 = fmaxf(acc3, 0.f);

  uint2 zm =
      *(const uint2*)(Zb + (size_t)node * 768 + 512 + (size_t)(lane & 31) * 8);
  float q0 = fmaxf(__uint_as_float(zm.x << 16), 0.f);
  float q1 = fmaxf(__uint_as_float(zm.x & 0xffff0000u), 0.f);
  float q2 = fmaxf(__uint_as_float(zm.y << 16), 0.f);
  float q3 = fmaxf(__uint_as_float(zm.y & 0xffff0000u), 0.f);

  const float* av_b = isHigh ? a_high : a_low;
  float4 ab = *(const float4*)&av_b[dbase];
  float4 am = *(const float4*)&a_mlp[dbase];
  float v1 = h0 * ab.x + h1 * ab.y + h2 * ab.z + h3 * ab.w;
  float v2 = isHigh ? 0.f : (q0 * am.x + q1 * am.y + q2 * am.z + q3 * am.w);
#pragma unroll
  for (int off = 1; off < 32; off <<= 1) {
    v1 += __shfl_xor(v1, off);
    v2 += __shfl_xor(v2, off);
  }
  float s_lo = __shfl(v1, 0);
  float s_hi = __shfl(v1, 32);
  float s_ml = __shfl(v2, 0);

  float g0 = 1.f / (1.f + __expf(-s_lo));
  float g1 = 1.f / (1.f + __expf(-s_hi));
  float g2 = 1.f / (1.f + __expf(-s_ml));
  const float inv3 = 1.f / 3.f;
  float m0 = (g0 * att_vec[0] + g1 * att_vec[3] + g2 * att_vec[6]) * inv3;
  float m1 = (g0 * att_vec[1] + g1 * att_vec[4] + g2 * att_vec[7]) * inv3;
  float m2 = (g0 * att_vec[2] + g1 * att_vec[5] + g2 * att_vec[8]) * inv3;
  float mx = fmaxf(m0, fmaxf(m1, m2));
  float e0 = __expf(m0 - mx), e1 = __expf(m1 - mx), e2 = __expf(m2 - mx);
  float inv = 1.f / (e0 + e1 + e2);
  float c0 = 3.f * inv * e0, c1 = 3.f * inv * e1, c2 = 3.f * inv * e2;

  float hh0 = __shfl_xor(h0, 32);
  float hh1 = __shfl_xor(h1, 32);
  float hh2 = __shfl_xor(h2, 32);
  float hh3 = __shfl_xor(h3, 32);

  if (!isHigh) {
    float4 o;
    o.x = c0 * h0 + c1 * hh0 + c2 * q0;
    o.y = c0 * h1 + c1 * hh1 + c2 * q1;
    o.z = c0 * h2 + c1 * hh2 + c2 * q2;
    o.w = c0 * h3 + c1 * hh3 + c2 * q3;
    *(float4*)&out[(size_t)node * D_OUT + dbase] = o;
  }
}

// ---------------------------------------------------------------------------
extern "C" void kernel_launch(void* const* d_in, const int* in_sizes, int n_in,
                              void* d_out, int out_size, void* d_ws,
                              size_t ws_size, hipStream_t stream) {
  const float* x    = (const float*)d_in[0];
  const int*   esrc = (const int*)d_in[1];
  const int*   edst = (const int*)d_in[2];
  const float* wlo  = (const float*)d_in[3];
  const float* whi  = (const float*)d_in[4];
  const float* Wl   = (const float*)d_in[6];
  const float* Wh   = (const float*)d_in[7];
  const float* Wm   = (const float*)d_in[8];
  const float* alo  = (const float*)d_in[9];
  const float* ahi  = (const float*)d_in[10];
  const float* amlp = (const float*)d_in[11];
  const float* av   = (const float*)d_in[12];
  float* out = (float*)d_out;

  const int N = in_sizes[0] / D_IN;  // 100000
  const int E = in_sizes[1];         // 1600000
  const int NB1 = (N + 127) >> 7;    // coarse buckets (782)
  const int M = NB1 * NHB;           // bh entries (200192)

  char* ws = (char*)d_ws;
  size_t off = 0;
  auto carve = [&](size_t bytes) -> void* {
    void* p = ws + off;
    off = (off + bytes + 255) & ~(size_t)255;
    return p;
  };
  unsigned short* Z      = (unsigned short*)carve((size_t)N * DZ * 2);
  unsigned short* xb     = (unsigned short*)carve((size_t)N * D_IN * 2);
  unsigned short* Bpack  = (unsigned short*)carve(98304 * 2);
  int*   bh     = (int*)carve((size_t)M * 4);
  int*   bhscan = (int*)carve((size_t)M * 4);
  int*   bsum   = (int*)carve(256 * 4);
  int*   rowptr = (int*)carve((size_t)(N + 1) * 4);
  uint2* tmp    = (uint2*)carve((size_t)E * 8);
  uint2* meta   = (uint2*)carve((size_t)E * 8);

  int n8 = in_sizes[0] / 8;
  int nxb = (n8 + 255) / 256;

  // coarse histogram + prep (fused roles)
  hist_prep_kernel<<<NHB + 384 + nxb, 256, 0, stream>>>(Wl, Wh, Wm, Bpack, x,
                                                        xb, n8, edst, bh, E,
                                                        NB1);
  // exclusive scan of bh (scan3 folded into consumers)
  int nb1s = (M + 1023) / 1024;
  scan1_kernel<<<nb1s, 256, 0, stream>>>(bh, bhscan, bsum, M);
  scan2_kernel<<<1, 256, 0, stream>>>(bsum, nb1s);

  // fused gemm + coarse scatter (no global atomics)
  int ngemm = (N + 63) / 64;
  gemm_sort_kernel<<<ngemm + NHB, 512, 0, stream>>>(
      xb, Bpack, Z, N, esrc, edst, wlo, whi, bhscan, bsum, tmp, E, NB1);

  // fine sort within buckets -> meta + rowptr
  fine_kernel<<<NB1, 256, 0, stream>>>(tmp, bhscan, bsum, meta, rowptr, NB1, N,
                                       E);

  node_kernel<<<(N + 1) / 2, 128, 0, stream>>>(Z, rowptr, meta, alo, ahi, amlp,
                                               av, out, N);
}

// Round 12
// 420.350 us; speedup vs baseline: 1.3949x; 1.0726x over previous
//
#include <hip/hip_runtime.h>
#include <hip/hip_bf16.h>
#include <math.h>

#define D_IN   256
#define D_OUT  128
#define DZ     384   // [low | high | mlp] bf16, 768 B per row
#define NHB    256   // coarse-sort blocks (hist + scatter replay partition)

typedef __attribute__((ext_vector_type(8))) short short8;
typedef __attribute__((ext_vector_type(4))) float floatx4;

__device__ __forceinline__ unsigned short f2bf(float f) {
  union { float f; unsigned u; } v; v.f = f;
  unsigned r = v.u + 0x7fffu + ((v.u >> 16) & 1u);  // RNE
  return (unsigned short)(r >> 16);
}

// ---------------------------------------------------------------------------
// FUSED coarse-histogram + prep. Three block roles:
//   bid < NHB          : LDS histogram of dst>>7 over this block's edge chunk
//                        -> bh[bucket*NHB + bid]   (no global atomics)
//   NHB..NHB+383       : repack [Wl|Wh|Wm] into MFMA B-fragment order
//   rest               : xcvt x fp32 -> bf16, 8 elems/thread
// ---------------------------------------------------------------------------
__global__ __launch_bounds__(256) void hist_prep_kernel(
    const float* __restrict__ Wl, const float* __restrict__ Wh,
    const float* __restrict__ Wm, unsigned short* __restrict__ Bpack,
    const float* __restrict__ x, unsigned short* __restrict__ xb, int n8,
    const int* __restrict__ dst, int* __restrict__ bh, int E, int NB1) {
  __shared__ int hist[1024];  // NB1 <= 1024 (N <= 131072)
  const int bid = blockIdx.x;
  const int t = threadIdx.x;
  if (bid < NHB) {
    for (int k = t; k < NB1; k += 256) hist[k] = 0;
    __syncthreads();
    const int chunk = (E + NHB - 1) / NHB;
    const int base = bid * chunk;
    const int lim = min(E, base + chunk);
    for (int e = base + t; e < lim; e += 256) atomicAdd(&hist[dst[e] >> 7], 1);
    __syncthreads();
    for (int k = t; k < NB1; k += 256) bh[k * NHB + bid] = hist[k];
  } else if (bid < NHB + 384) {
    // repack: frag f = kt*24+nt holds B[k=kt*32+quad*8+j][n=nt*16+(lane&15)]
    int tt = (bid - NHB) * 256 + t;  // 0..98303
    int j = tt & 7;
    int lane = (tt >> 3) & 63;
    int f = tt >> 9;  // 0..191
    int nt = f % 24, kt = f / 24;
    int k = kt * 32 + (lane >> 4) * 8 + j;
    int n_ = nt * 16 + (lane & 15);
    const float* W = (n_ < 128) ? Wl : (n_ < 256 ? Wh : Wm);
    Bpack[tt] = f2bf(W[k * D_OUT + (n_ & 127)]);
  } else {
    int i = (bid - NHB - 384) * 256 + t;
    if (i < n8) {
      const float4* p = (const float4*)x + (size_t)i * 2;
      float4 f0 = p[0], f1 = p[1];
      short8 o;
      o[0] = (short)f2bf(f0.x); o[1] = (short)f2bf(f0.y);
      o[2] = (short)f2bf(f0.z); o[3] = (short)f2bf(f0.w);
      o[4] = (short)f2bf(f1.x); o[5] = (short)f2bf(f1.y);
      o[6] = (short)f2bf(f1.z); o[7] = (short)f2bf(f1.w);
      ((short8*)xb)[i] = o;
    }
  }
}

// ---------------------------------------------------------------------------
// Exclusive scan over M = NB1*NHB ints. scan1 -> per-1024-chunk exclusive +
// chunk totals; scan2 -> exclusive scan of totals. Consumers read
// bhscan[i] + bsum[i>>10] directly (scan3 folded away).
// ---------------------------------------------------------------------------
__global__ __launch_bounds__(256) void scan1_kernel(
    const int* __restrict__ cnt, int* __restrict__ outp,
    int* __restrict__ bsum, int n) {
  __shared__ int sd[256];
  int t = threadIdx.x;
  int base = blockIdx.x * 1024 + t * 4;
  int v0 = base + 0 < n ? cnt[base + 0] : 0;
  int v1 = base + 1 < n ? cnt[base + 1] : 0;
  int v2 = base + 2 < n ? cnt[base + 2] : 0;
  int v3 = base + 3 < n ? cnt[base + 3] : 0;
  int tsum = v0 + v1 + v2 + v3;
  sd[t] = tsum;
  __syncthreads();
  for (int off = 1; off < 256; off <<= 1) {
    int add = (t >= off) ? sd[t - off] : 0;
    __syncthreads();
    sd[t] += add;
    __syncthreads();
  }
  int excl = sd[t] - tsum;
  if (base + 0 < n) outp[base + 0] = excl;
  if (base + 1 < n) outp[base + 1] = excl + v0;
  if (base + 2 < n) outp[base + 2] = excl + v0 + v1;
  if (base + 3 < n) outp[base + 3] = excl + v0 + v1 + v2;
  if (t == 255) bsum[blockIdx.x] = sd[255];
}

__global__ __launch_bounds__(256) void scan2_kernel(int* __restrict__ bsum,
                                                    int nb) {
  __shared__ int sd[256];
  int t = threadIdx.x;
  int v = t < nb ? bsum[t] : 0;
  sd[t] = v;
  __syncthreads();
  for (int off = 1; off < 256; off <<= 1) {
    int add = (t >= off) ? sd[t - off] : 0;
    __syncthreads();
    sd[t] += add;
    __syncthreads();
  }
  if (t < nb) bsum[t] = sd[t] - v;  // exclusive
}

// ---------------------------------------------------------------------------
// FUSED gemm + coarse scatter (even/odd role split, r6's proven pattern).
//   even ids < 2*NHB : replay edge chunk rb=bid>>1; positions from per-bucket
//                      LDS cursors seeded with bhscan[k*NHB+rb]+bsum fold
//                      -> tmp[pos] = {src | dlow7<<20, bf16(wl)|bf16(wh)<<16}
//   odd / remainder  : gemm tiles
// NEW (r12): A staged through LDS. r11 counters: MfmaUtil 6%, VALU 6%,
// 1.4 TB/s -> 88% of cycles stalled on the A-gather (16 discontiguous 64B
// segments per load instr at L2 latency). Fix: the 64-row A-tile is one
// LINEAR 32KB span of xb -> 4 rounds of fully-coalesced 16B/thread stores
// into LDS (XOR-swizzled chunk index, same XOR on read -> ~2-way banks for
// the ds_read_b128 fragment reads). K-loop then runs at LDS latency.
// Epilogue tile reuses the same 32KB LDS (barrier-protected union).
// ---------------------------------------------------------------------------
#define LDSROW 392  // shorts/row for the epilogue tile: 784 B (16B-aligned)
__global__ __launch_bounds__(512, 4) void gemm_sort_kernel(
    const unsigned short* __restrict__ xb,
    const unsigned short* __restrict__ Bpack, unsigned short* __restrict__ Z,
    int n_nodes, const int* __restrict__ src, const int* __restrict__ dst,
    const float* __restrict__ wlo, const float* __restrict__ whi,
    const int* __restrict__ bhscan, const int* __restrict__ bsum,
    uint2* __restrict__ tmp, int E, int NB1) {
  __shared__ unsigned short lds[16384];  // 32 KB: A-tile, then epilogue tile
  const int bid = blockIdx.x;

  int gemm_id;
  if (bid < 2 * NHB) {
    if ((bid & 1) == 0) {  // ---- coarse scatter block ----
      int rb = bid >> 1;
      int* cur = (int*)lds;
      int t = threadIdx.x;
      for (int k = t; k < NB1; k += 512) {
        int idx = k * NHB + rb;
        cur[k] = bhscan[idx] + bsum[idx >> 10];
      }
      __syncthreads();
      const int chunk = (E + NHB - 1) / NHB;
      const int base = rb * chunk;
      const int lim = min(E, base + chunk);
      for (int e = base + t; e < lim; e += 512) {
        int d = dst[e];
        int pos = atomicAdd(&cur[d >> 7], 1);  // LDS atomic
        unsigned wl = f2bf(wlo[e]), wh = f2bf(whi[e]);
        tmp[pos] = make_uint2((unsigned)src[e] | ((unsigned)(d & 127) << 20),
                              wl | (wh << 16));
      }
      return;
    }
    gemm_id = bid >> 1;
  } else {
    gemm_id = bid - 2 * NHB + NHB;
  }

  // ---- gemm block ----
  const int lane = threadIdx.x & 63;
  const int w = threadIdx.x >> 6;  // 0..7: column group (3 ctiles)
  const int rowbase = gemm_id * 64;
  const int m16 = lane & 15, quad = lane >> 4;

  // cooperative A staging: 64 rows x 512 B = linear 32 KB of xb.
  // chunk c (16B) within row is stored at pc = (c&~7)|((c^row)&7).
  {
    const short8* xs = (const short8*)xb;
#pragma unroll
    for (int i = 0; i < 4; i++) {
      int idx = i * 512 + threadIdx.x;  // 0..2047
      int row = idx >> 5, c = idx & 31;
      int gr = rowbase + row;
      if (gr > n_nodes - 1) gr = n_nodes - 1;  // clamp; stores are guarded
      int pc = (c & ~7) | ((c ^ row) & 7);
      ((short8*)lds)[row * 32 + pc] = xs[(size_t)gr * 32 + c];
    }
  }
  __syncthreads();

  floatx4 acc[4][3];
#pragma unroll
  for (int s = 0; s < 4; s++)
#pragma unroll
    for (int c = 0; c < 3; c++) acc[s][c] = (floatx4)(0.f);

  const short8* bp = (const short8*)Bpack + lane;

#pragma unroll
  for (int kt = 0; kt < 8; kt++) {
    short8 a[4];
#pragma unroll
    for (int s = 0; s < 4; s++) {
      int r_ = s * 16 + m16;
      int c_ = kt * 4 + quad;
      int pc = (c_ & ~7) | ((c_ ^ r_) & 7);
      a[s] = ((const short8*)lds)[r_ * 32 + pc];
    }
#pragma unroll
    for (int c = 0; c < 3; c++) {
      short8 b = bp[(kt * 24 + w * 3 + c) * 64];
#pragma unroll
      for (int s = 0; s < 4; s++)
        acc[s][c] =
            __builtin_amdgcn_mfma_f32_16x16x32_bf16(a[s], b, acc[s][c], 0, 0, 0);
    }
  }

  __syncthreads();  // all A-tile reads done before epilogue overwrites lds
  unsigned short* tile = lds;

  // two-pass LDS epilogue: strips {0,1} then {2,3} through a 32-row tile.
  // C-layout: local row = s*16+quad*4+r, col = (w*3+c)*16+m16.
#pragma unroll
  for (int half = 0; half < 2; half++) {
    if (half) __syncthreads();  // tile reuse: wait for pass-0 loads done
#pragma unroll
    for (int s = 0; s < 2; s++)
#pragma unroll
      for (int c = 0; c < 3; c++)
#pragma unroll
        for (int r = 0; r < 4; r++)
          tile[(s * 16 + quad * 4 + r) * LDSROW + (w * 3 + c) * 16 + m16] =
              f2bf(acc[half * 2 + s][c][r]);
    __syncthreads();
    // coalesced store: 32 rows x 48 chunks of 16B = 1536 chunks / 512 thr
#pragma unroll
    for (int it = 0; it < 3; it++) {
      int chunk = it * 512 + threadIdx.x;
      int row = chunk / 48, col = (chunk % 48) * 8;
      int grow = rowbase + half * 32 + row;
      if (grow < n_nodes)
        *(short8*)(Z + (size_t)grow * DZ + col) =
            *(const short8*)&tile[row * LDSROW + col];
    }
  }
}

// ---------------------------------------------------------------------------
// Fine pass: one block per coarse bucket (128 nodes, ~2046 edges).
// LDS 128-bin histogram + LDS scan -> final meta grouped by dst + rowptr.
// All reads/writes are streaming or segment-local (L2-resident).
// ---------------------------------------------------------------------------
__global__ __launch_bounds__(256) void fine_kernel(
    const uint2* __restrict__ tmp, const int* __restrict__ bhscan,
    const int* __restrict__ bsum, uint2* __restrict__ meta,
    int* __restrict__ rowptr, int NB1, int n, int E) {
  __shared__ int fh[128];
  __shared__ int sd[128];
  __shared__ int cur[128];
  const int b = blockIdx.x;
  const int t = threadIdx.x;
  auto scanidx = [&](int i) { return bhscan[i] + bsum[i >> 10]; };
  const int s0 = scanidx(b * NHB);
  const int s1 = (b == NB1 - 1) ? E : scanidx((b + 1) * NHB);

  if (t < 128) fh[t] = 0;
  __syncthreads();
  for (int i = s0 + t; i < s1; i += 256)
    atomicAdd(&fh[(tmp[i].x >> 20) & 127], 1);
  __syncthreads();

  // exclusive scan of the 128 bins
  if (t < 128) sd[t] = fh[t];
  __syncthreads();
  for (int off = 1; off < 128; off <<= 1) {
    int add = (t >= off && t < 128) ? sd[t - off] : 0;
    __syncthreads();
    if (t < 128) sd[t] += add;
    __syncthreads();
  }
  if (t < 128) {
    int excl = sd[t] - fh[t];
    cur[t] = excl;
    int node = b * 128 + t;
    if (node < n) rowptr[node] = s0 + excl;
  }
  if (b == 0 && t == 0) rowptr[n] = E;
  __syncthreads();

  for (int i = s0 + t; i < s1; i += 256) {
    uint2 v = tmp[i];
    int d = (v.x >> 20) & 127;
    int pos = s0 + atomicAdd(&cur[d], 1);  // LDS atomic
    meta[pos] = make_uint2(v.x & 0xFFFFFu, v.y);
  }
}

// ---------------------------------------------------------------------------
// K_node: CSR gather + relu + attention3. 128-thr blocks = 2 independent
// waves = 2 nodes. readfirstlane(node) -> rowptr/meta via scalar loads.
// Lane l<32: low dims 4l..4l+3; l>=32: high dims. One uint2 Z load per edge,
// unroll x8. (round-0 structure: best measured at ~123-125us, stable across
// three gather variants -> near its L3-path floor)
// ---------------------------------------------------------------------------
__global__ __launch_bounds__(128) void node_kernel(
    const unsigned short* __restrict__ Zh, const int* __restrict__ rowptr,
    const uint2* __restrict__ meta, const float* __restrict__ a_low,
    const float* __restrict__ a_high, const float* __restrict__ a_mlp,
    const float* __restrict__ att_vec, float* __restrict__ out, int n_nodes) {
  int node = blockIdx.x * 2 + (threadIdx.x >> 6);
  if (node >= n_nodes) return;
  node = __builtin_amdgcn_readfirstlane(node);  // wave-uniform -> s_loads
  const int lane = threadIdx.x & 63;
  const int isHigh = lane >> 5;
  const int dbase = (lane & 31) * 4;
  const char* Zb = (const char*)Zh;

  const int start = rowptr[node];
  const int end = rowptr[node + 1];

  float acc0 = 0.f, acc1 = 0.f, acc2 = 0.f, acc3 = 0.f;
  auto wsel = [&](unsigned p) {
    return __uint_as_float(isHigh ? (p & 0xffff0000u) : (p << 16));
  };
  auto step = [&](uint2 z, float wv) {
    acc0 += wv * __uint_as_float(z.x << 16);
    acc1 += wv * __uint_as_float(z.x & 0xffff0000u);
    acc2 += wv * __uint_as_float(z.y << 16);
    acc3 += wv * __uint_as_float(z.y & 0xffff0000u);
  };

  int j = start;
  const int nfull = (end - start) & ~7;
  for (; j < start + nfull; j += 8) {
    uint2 m[8], z[8];
#pragma unroll
    for (int u = 0; u < 8; u++) m[u] = meta[j + u];
#pragma unroll
    for (int u = 0; u < 8; u++)
      z[u] = *(const uint2*)(Zb + (size_t)m[u].x * 768 + lane * 8);
#pragma unroll
    for (int u = 0; u < 8; u++) step(z[u], wsel(m[u].y));
  }
  for (; j < end; j++) {
    uint2 m0 = meta[j];
    uint2 z0 = *(const uint2*)(Zb + (size_t)m0.x * 768 + lane * 8);
    step(z0, wsel(m0.y));
  }

  float h0 = fmaxf(acc0, 0.f), h1 = fmaxf(acc1, 0.f);
  float h2 = fmaxf(acc2, 0.f), h3 = fmaxf(acc3, 0.f);

  uint2 zm =
      *(const uint2*)(Zb + (size_t)node * 768 + 512 + (size_t)(lane & 31) * 8);
  float q0 = fmaxf(__uint_as_float(zm.x << 16), 0.f);
  float q1 = fmaxf(__uint_as_float(zm.x & 0xffff0000u), 0.f);
  float q2 = fmaxf(__uint_as_float(zm.y << 16), 0.f);
  float q3 = fmaxf(__uint_as_float(zm.y & 0xffff0000u), 0.f);

  const float* av_b = isHigh ? a_high : a_low;
  float4 ab = *(const float4*)&av_b[dbase];
  float4 am = *(const float4*)&a_mlp[dbase];
  float v1 = h0 * ab.x + h1 * ab.y + h2 * ab.z + h3 * ab.w;
  float v2 = isHigh ? 0.f : (q0 * am.x + q1 * am.y + q2 * am.z + q3 * am.w);
#pragma unroll
  for (int off = 1; off < 32; off <<= 1) {
    v1 += __shfl_xor(v1, off);
    v2 += __shfl_xor(v2, off);
  }
  float s_lo = __shfl(v1, 0);
  float s_hi = __shfl(v1, 32);
  float s_ml = __shfl(v2, 0);

  float g0 = 1.f / (1.f + __expf(-s_lo));
  float g1 = 1.f / (1.f + __expf(-s_hi));
  float g2 = 1.f / (1.f + __expf(-s_ml));
  const float inv3 = 1.f / 3.f;
  float m0 = (g0 * att_vec[0] + g1 * att_vec[3] + g2 * att_vec[6]) * inv3;
  float m1 = (g0 * att_vec[1] + g1 * att_vec[4] + g2 * att_vec[7]) * inv3;
  float m2 = (g0 * att_vec[2] + g1 * att_vec[5] + g2 * att_vec[8]) * inv3;
  float mx = fmaxf(m0, fmaxf(m1, m2));
  float e0 = __expf(m0 - mx), e1 = __expf(m1 - mx), e2 = __expf(m2 - mx);
  float inv = 1.f / (e0 + e1 + e2);
  float c0 = 3.f * inv * e0, c1 = 3.f * inv * e1, c2 = 3.f * inv * e2;

  float hh0 = __shfl_xor(h0, 32);
  float hh1 = __shfl_xor(h1, 32);
  float hh2 = __shfl_xor(h2, 32);
  float hh3 = __shfl_xor(h3, 32);

  if (!isHigh) {
    float4 o;
    o.x = c0 * h0 + c1 * hh0 + c2 * q0;
    o.y = c0 * h1 + c1 * hh1 + c2 * q1;
    o.z = c0 * h2 + c1 * hh2 + c2 * q2;
    o.w = c0 * h3 + c1 * hh3 + c2 * q3;
    *(float4*)&out[(size_t)node * D_OUT + dbase] = o;
  }
}

// ---------------------------------------------------------------------------
extern "C" void kernel_launch(void* const* d_in, const int* in_sizes, int n_in,
                              void* d_out, int out_size, void* d_ws,
                              size_t ws_size, hipStream_t stream) {
  const float* x    = (const float*)d_in[0];
  const int*   esrc = (const int*)d_in[1];
  const int*   edst = (const int*)d_in[2];
  const float* wlo  = (const float*)d_in[3];
  const float* whi  = (const float*)d_in[4];
  const float* Wl   = (const float*)d_in[6];
  const float* Wh   = (const float*)d_in[7];
  const float* Wm   = (const float*)d_in[8];
  const float* alo  = (const float*)d_in[9];
  const float* ahi  = (const float*)d_in[10];
  const float* amlp = (const float*)d_in[11];
  const float* av   = (const float*)d_in[12];
  float* out = (float*)d_out;

  const int N = in_sizes[0] / D_IN;  // 100000
  const int E = in_sizes[1];         // 1600000
  const int NB1 = (N + 127) >> 7;    // coarse buckets (782)
  const int M = NB1 * NHB;           // bh entries (200192)

  char* ws = (char*)d_ws;
  size_t off = 0;
  auto carve = [&](size_t bytes) -> void* {
    void* p = ws + off;
    off = (off + bytes + 255) & ~(size_t)255;
    return p;
  };
  unsigned short* Z      = (unsigned short*)carve((size_t)N * DZ * 2);
  unsigned short* xb     = (unsigned short*)carve((size_t)N * D_IN * 2);
  unsigned short* Bpack  = (unsigned short*)carve(98304 * 2);
  int*   bh     = (int*)carve((size_t)M * 4);
  int*   bhscan = (int*)carve((size_t)M * 4);
  int*   bsum   = (int*)carve(256 * 4);
  int*   rowptr = (int*)carve((size_t)(N + 1) * 4);
  uint2* tmp    = (uint2*)carve((size_t)E * 8);
  uint2* meta   = (uint2*)carve((size_t)E * 8);

  int n8 = in_sizes[0] / 8;
  int nxb = (n8 + 255) / 256;

  // coarse histogram + prep (fused roles)
  hist_prep_kernel<<<NHB + 384 + nxb, 256, 0, stream>>>(Wl, Wh, Wm, Bpack, x,
                                                        xb, n8, edst, bh, E,
                                                        NB1);
  // exclusive scan of bh (scan3 folded into consumers)
  int nb1s = (M + 1023) / 1024;
  scan1_kernel<<<nb1s, 256, 0, stream>>>(bh, bhscan, bsum, M);
  scan2_kernel<<<1, 256, 0, stream>>>(bsum, nb1s);

  // fused gemm + coarse scatter (no global atomics)
  int ngemm = (N + 63) / 64;
  gemm_sort_kernel<<<ngemm + NHB, 512, 0, stream>>>(
      xb, Bpack, Z, N, esrc, edst, wlo, whi, bhscan, bsum, tmp, E, NB1);

  // fine sort within buckets -> meta + rowptr
  fine_kernel<<<NB1, 256, 0, stream>>>(tmp, bhscan, bsum, meta, rowptr, NB1, N,
                                       E);

  node_kernel<<<(N + 1) / 2, 128, 0, stream>>>(Z, rowptr, meta, alo, ahi, amlp,
                                               av, out, N);
}

// Round 13
// 418.182 us; speedup vs baseline: 1.4022x; 1.0052x over previous
//
#include <hip/hip_runtime.h>
#include <hip/hip_bf16.h>
#include <math.h>

#define D_IN   256
#define D_OUT  128
#define NHB    256   // coarse-sort blocks (hist + scatter replay partition)

typedef __attribute__((ext_vector_type(8))) short short8;
typedef __attribute__((ext_vector_type(4))) float floatx4;

__device__ __forceinline__ unsigned short f2bf(float f) {
  union { float f; unsigned u; } v; v.f = f;
  unsigned r = v.u + 0x7fffu + ((v.u >> 16) & 1u);  // RNE
  return (unsigned short)(r >> 16);
}

// ---------------------------------------------------------------------------
// FUSED coarse-histogram + prep. Three block roles:
//   bid < NHB          : LDS histogram of dst>>7 over this block's edge chunk
//                        -> bh[bucket*NHB + bid]   (no global atomics)
//   NHB..NHB+383       : repack [Wl|Wh|Wm] into MFMA B-fragment order
//   rest               : xcvt x fp32 -> bf16, 8 elems/thread
// ---------------------------------------------------------------------------
__global__ __launch_bounds__(256) void hist_prep_kernel(
    const float* __restrict__ Wl, const float* __restrict__ Wh,
    const float* __restrict__ Wm, unsigned short* __restrict__ Bpack,
    const float* __restrict__ x, unsigned short* __restrict__ xb, int n8,
    const int* __restrict__ dst, int* __restrict__ bh, int E, int NB1) {
  __shared__ int hist[1024];  // NB1 <= 1024 (N <= 131072)
  const int bid = blockIdx.x;
  const int t = threadIdx.x;
  if (bid < NHB) {
    for (int k = t; k < NB1; k += 256) hist[k] = 0;
    __syncthreads();
    const int chunk = (E + NHB - 1) / NHB;
    const int base = bid * chunk;
    const int lim = min(E, base + chunk);
    for (int e = base + t; e < lim; e += 256) atomicAdd(&hist[dst[e] >> 7], 1);
    __syncthreads();
    for (int k = t; k < NB1; k += 256) bh[k * NHB + bid] = hist[k];
  } else if (bid < NHB + 384) {
    // repack: frag f = kt*24+nt holds B[k=kt*32+quad*8+j][n=nt*16+(lane&15)]
    int tt = (bid - NHB) * 256 + t;  // 0..98303
    int j = tt & 7;
    int lane = (tt >> 3) & 63;
    int f = tt >> 9;  // 0..191
    int nt = f % 24, kt = f / 24;
    int k = kt * 32 + (lane >> 4) * 8 + j;
    int n_ = nt * 16 + (lane & 15);
    const float* W = (n_ < 128) ? Wl : (n_ < 256 ? Wh : Wm);
    Bpack[tt] = f2bf(W[k * D_OUT + (n_ & 127)]);
  } else {
    int i = (bid - NHB - 384) * 256 + t;
    if (i < n8) {
      const float4* p = (const float4*)x + (size_t)i * 2;
      float4 f0 = p[0], f1 = p[1];
      short8 o;
      o[0] = (short)f2bf(f0.x); o[1] = (short)f2bf(f0.y);
      o[2] = (short)f2bf(f0.z); o[3] = (short)f2bf(f0.w);
      o[4] = (short)f2bf(f1.x); o[5] = (short)f2bf(f1.y);
      o[6] = (short)f2bf(f1.z); o[7] = (short)f2bf(f1.w);
      ((short8*)xb)[i] = o;
    }
  }
}

// ---------------------------------------------------------------------------
// Exclusive scan over M = NB1*NHB ints. scan1 -> per-1024-chunk exclusive +
// chunk totals; scan2 -> exclusive scan of totals. Consumers read
// bhscan[i] + bsum[i>>10] directly (scan3 folded away).
// ---------------------------------------------------------------------------
__global__ __launch_bounds__(256) void scan1_kernel(
    const int* __restrict__ cnt, int* __restrict__ outp,
    int* __restrict__ bsum, int n) {
  __shared__ int sd[256];
  int t = threadIdx.x;
  int base = blockIdx.x * 1024 + t * 4;
  int v0 = base + 0 < n ? cnt[base + 0] : 0;
  int v1 = base + 1 < n ? cnt[base + 1] : 0;
  int v2 = base + 2 < n ? cnt[base + 2] : 0;
  int v3 = base + 3 < n ? cnt[base + 3] : 0;
  int tsum = v0 + v1 + v2 + v3;
  sd[t] = tsum;
  __syncthreads();
  for (int off = 1; off < 256; off <<= 1) {
    int add = (t >= off) ? sd[t - off] : 0;
    __syncthreads();
    sd[t] += add;
    __syncthreads();
  }
  int excl = sd[t] - tsum;
  if (base + 0 < n) outp[base + 0] = excl;
  if (base + 1 < n) outp[base + 1] = excl + v0;
  if (base + 2 < n) outp[base + 2] = excl + v0 + v1;
  if (base + 3 < n) outp[base + 3] = excl + v0 + v1 + v2;
  if (t == 255) bsum[blockIdx.x] = sd[255];
}

__global__ __launch_bounds__(256) void scan2_kernel(int* __restrict__ bsum,
                                                    int nb) {
  __shared__ int sd[256];
  int t = threadIdx.x;
  int v = t < nb ? bsum[t] : 0;
  sd[t] = v;
  __syncthreads();
  for (int off = 1; off < 256; off <<= 1) {
    int add = (t >= off) ? sd[t - off] : 0;
    __syncthreads();
    sd[t] += add;
    __syncthreads();
  }
  if (t < nb) bsum[t] = sd[t] - v;  // exclusive
}

// ---------------------------------------------------------------------------
// FUSED gemm + coarse scatter (even/odd role split, r6's proven pattern).
//   even ids < 2*NHB : replay edge chunk rb=bid>>1; positions from per-bucket
//                      LDS cursors seeded with bhscan[k*NHB+rb]+bsum fold
//                      -> tmp[pos] = {src | dlow7<<20, bf16(wl)|bf16(wh)<<16}
//   odd / remainder  : gemm tiles
// A staged through LDS (r12 win: 124 -> ~93us; coalesced linear 32KB span,
// XOR-swizzled chunks, K-loop at LDS latency). Epilogue now writes SPLIT
// output: Zg = [low|high] 512B gather rows (hot set 51MB) and Zm plane
// (25.6MB, once-read) — shrinks node's L2-hot working set.
// ---------------------------------------------------------------------------
#define LDSROW 392  // shorts/row for the epilogue tile: 784 B (16B-aligned)
__global__ __launch_bounds__(512, 4) void gemm_sort_kernel(
    const unsigned short* __restrict__ xb,
    const unsigned short* __restrict__ Bpack, unsigned short* __restrict__ Zg,
    unsigned short* __restrict__ Zm, int n_nodes, const int* __restrict__ src,
    const int* __restrict__ dst, const float* __restrict__ wlo,
    const float* __restrict__ whi, const int* __restrict__ bhscan,
    const int* __restrict__ bsum, uint2* __restrict__ tmp, int E, int NB1) {
  __shared__ unsigned short lds[16384];  // 32 KB: A-tile, then epilogue tile
  const int bid = blockIdx.x;

  int gemm_id;
  if (bid < 2 * NHB) {
    if ((bid & 1) == 0) {  // ---- coarse scatter block ----
      int rb = bid >> 1;
      int* cur = (int*)lds;
      int t = threadIdx.x;
      for (int k = t; k < NB1; k += 512) {
        int idx = k * NHB + rb;
        cur[k] = bhscan[idx] + bsum[idx >> 10];
      }
      __syncthreads();
      const int chunk = (E + NHB - 1) / NHB;
      const int base = rb * chunk;
      const int lim = min(E, base + chunk);
      for (int e = base + t; e < lim; e += 512) {
        int d = dst[e];
        int pos = atomicAdd(&cur[d >> 7], 1);  // LDS atomic
        unsigned wl = f2bf(wlo[e]), wh = f2bf(whi[e]);
        tmp[pos] = make_uint2((unsigned)src[e] | ((unsigned)(d & 127) << 20),
                              wl | (wh << 16));
      }
      return;
    }
    gemm_id = bid >> 1;
  } else {
    gemm_id = bid - 2 * NHB + NHB;
  }

  // ---- gemm block ----
  const int lane = threadIdx.x & 63;
  const int w = threadIdx.x >> 6;  // 0..7: column group (3 ctiles)
  const int rowbase = gemm_id * 64;
  const int m16 = lane & 15, quad = lane >> 4;

  // cooperative A staging: 64 rows x 512 B = linear 32 KB of xb.
  // chunk c (16B) within row is stored at pc = (c&~7)|((c^row)&7).
  {
    const short8* xs = (const short8*)xb;
#pragma unroll
    for (int i = 0; i < 4; i++) {
      int idx = i * 512 + threadIdx.x;  // 0..2047
      int row = idx >> 5, c = idx & 31;
      int gr = rowbase + row;
      if (gr > n_nodes - 1) gr = n_nodes - 1;  // clamp; stores are guarded
      int pc = (c & ~7) | ((c ^ row) & 7);
      ((short8*)lds)[row * 32 + pc] = xs[(size_t)gr * 32 + c];
    }
  }
  __syncthreads();

  floatx4 acc[4][3];
#pragma unroll
  for (int s = 0; s < 4; s++)
#pragma unroll
    for (int c = 0; c < 3; c++) acc[s][c] = (floatx4)(0.f);

  const short8* bp = (const short8*)Bpack + lane;

#pragma unroll
  for (int kt = 0; kt < 8; kt++) {
    short8 a[4];
#pragma unroll
    for (int s = 0; s < 4; s++) {
      int r_ = s * 16 + m16;
      int c_ = kt * 4 + quad;
      int pc = (c_ & ~7) | ((c_ ^ r_) & 7);
      a[s] = ((const short8*)lds)[r_ * 32 + pc];
    }
#pragma unroll
    for (int c = 0; c < 3; c++) {
      short8 b = bp[(kt * 24 + w * 3 + c) * 64];
#pragma unroll
      for (int s = 0; s < 4; s++)
        acc[s][c] =
            __builtin_amdgcn_mfma_f32_16x16x32_bf16(a[s], b, acc[s][c], 0, 0, 0);
    }
  }

  __syncthreads();  // all A-tile reads done before epilogue overwrites lds
  unsigned short* tile = lds;

  // two-pass LDS epilogue: strips {0,1} then {2,3} through a 32-row tile.
  // C-layout: local row = s*16+quad*4+r, col = (w*3+c)*16+m16.
  // chunk c8 0..31 -> Zg (512B gather row); 32..47 -> Zm plane.
#pragma unroll
  for (int half = 0; half < 2; half++) {
    if (half) __syncthreads();  // tile reuse: wait for pass-0 loads done
#pragma unroll
    for (int s = 0; s < 2; s++)
#pragma unroll
      for (int c = 0; c < 3; c++)
#pragma unroll
        for (int r = 0; r < 4; r++)
          tile[(s * 16 + quad * 4 + r) * LDSROW + (w * 3 + c) * 16 + m16] =
              f2bf(acc[half * 2 + s][c][r]);
    __syncthreads();
    // coalesced store: 32 rows x 48 chunks of 16B = 1536 chunks / 512 thr
#pragma unroll
    for (int it = 0; it < 3; it++) {
      int chunk = it * 512 + threadIdx.x;
      int row = chunk / 48, c8 = chunk % 48;
      int grow = rowbase + half * 32 + row;
      if (grow < n_nodes) {
        short8 v = *(const short8*)&tile[row * LDSROW + c8 * 8];
        if (c8 < 32)
          *(short8*)(Zg + (size_t)grow * 256 + c8 * 8) = v;
        else
          *(short8*)(Zm + (size_t)grow * 128 + (c8 - 32) * 8) = v;
      }
    }
  }
}

// ---------------------------------------------------------------------------
// Fine pass: one block per coarse bucket (128 nodes, ~2046 edges).
// LDS 128-bin histogram + LDS scan -> final meta grouped by dst + rowptr.
// ---------------------------------------------------------------------------
__global__ __launch_bounds__(256) void fine_kernel(
    const uint2* __restrict__ tmp, const int* __restrict__ bhscan,
    const int* __restrict__ bsum, uint2* __restrict__ meta,
    int* __restrict__ rowptr, int NB1, int n, int E) {
  __shared__ int fh[128];
  __shared__ int sd[128];
  __shared__ int cur[128];
  const int b = blockIdx.x;
  const int t = threadIdx.x;
  auto scanidx = [&](int i) { return bhscan[i] + bsum[i >> 10]; };
  const int s0 = scanidx(b * NHB);
  const int s1 = (b == NB1 - 1) ? E : scanidx((b + 1) * NHB);

  if (t < 128) fh[t] = 0;
  __syncthreads();
  for (int i = s0 + t; i < s1; i += 256)
    atomicAdd(&fh[(tmp[i].x >> 20) & 127], 1);
  __syncthreads();

  // exclusive scan of the 128 bins
  if (t < 128) sd[t] = fh[t];
  __syncthreads();
  for (int off = 1; off < 128; off <<= 1) {
    int add = (t >= off && t < 128) ? sd[t - off] : 0;
    __syncthreads();
    if (t < 128) sd[t] += add;
    __syncthreads();
  }
  if (t < 128) {
    int excl = sd[t] - fh[t];
    cur[t] = excl;
    int node = b * 128 + t;
    if (node < n) rowptr[node] = s0 + excl;
  }
  if (b == 0 && t == 0) rowptr[n] = E;
  __syncthreads();

  for (int i = s0 + t; i < s1; i += 256) {
    uint2 v = tmp[i];
    int d = (v.x >> 20) & 127;
    int pos = s0 + atomicAdd(&cur[d], 1);  // LDS atomic
    meta[pos] = make_uint2(v.x & 0xFFFFFu, v.y);
  }
}

// ---------------------------------------------------------------------------
// K_node: CSR gather + relu + attention3. 128-thr blocks = 2 independent
// waves = 2 nodes. Lane l<32: low dims 4l..4l+3; l>=32: high dims. One
// uint2 Zg load per edge (512B power-of-2 rows, hot set 51MB), unroll x8.
// Streams (meta, Zm, out) use non-temporal hints so they don't evict Zg
// from L2 — the gather's 16x reuse is the whole game.
// ---------------------------------------------------------------------------
__global__ __launch_bounds__(128) void node_kernel(
    const unsigned short* __restrict__ Zg, const unsigned short* __restrict__ Zm,
    const int* __restrict__ rowptr, const unsigned long long* __restrict__ meta,
    const float* __restrict__ a_low, const float* __restrict__ a_high,
    const float* __restrict__ a_mlp, const float* __restrict__ att_vec,
    float* __restrict__ out, int n_nodes) {
  int node = blockIdx.x * 2 + (threadIdx.x >> 6);
  if (node >= n_nodes) return;
  node = __builtin_amdgcn_readfirstlane(node);  // wave-uniform -> s_loads
  const int lane = threadIdx.x & 63;
  const int isHigh = lane >> 5;
  const int dbase = (lane & 31) * 4;
  const char* Zb = (const char*)Zg;

  const int start = rowptr[node];
  const int end = rowptr[node + 1];

  float acc0 = 0.f, acc1 = 0.f, acc2 = 0.f, acc3 = 0.f;
  auto wsel = [&](unsigned p) {
    return __uint_as_float(isHigh ? (p & 0xffff0000u) : (p << 16));
  };
  auto step = [&](uint2 z, float wv) {
    acc0 += wv * __uint_as_float(z.x << 16);
    acc1 += wv * __uint_as_float(z.x & 0xffff0000u);
    acc2 += wv * __uint_as_float(z.y << 16);
    acc3 += wv * __uint_as_float(z.y & 0xffff0000u);
  };

  int j = start;
  const int nfull = (end - start) & ~7;
  for (; j < start + nfull; j += 8) {
    unsigned long long m[8];
    uint2 z[8];
#pragma unroll
    for (int u = 0; u < 8; u++) m[u] = __builtin_nontemporal_load(&meta[j + u]);
#pragma unroll
    for (int u = 0; u < 8; u++)
      z[u] = *(const uint2*)(Zb + ((size_t)(unsigned)m[u]) * 512 + lane * 8);
#pragma unroll
    for (int u = 0; u < 8; u++) step(z[u], wsel((unsigned)(m[u] >> 32)));
  }
  for (; j < end; j++) {
    unsigned long long m0 = __builtin_nontemporal_load(&meta[j]);
    uint2 z0 = *(const uint2*)(Zb + ((size_t)(unsigned)m0) * 512 + lane * 8);
    step(z0, wsel((unsigned)(m0 >> 32)));
  }

  float h0 = fmaxf(acc0, 0.f), h1 = fmaxf(acc1, 0.f);
  float h2 = fmaxf(acc2, 0.f), h3 = fmaxf(acc3, 0.f);

  unsigned long long zmq = __builtin_nontemporal_load(
      (const unsigned long long*)((const char*)Zm + (size_t)node * 256 +
                                  (size_t)(lane & 31) * 8));
  unsigned zmx = (unsigned)zmq, zmy = (unsigned)(zmq >> 32);
  float q0 = fmaxf(__uint_as_float(zmx << 16), 0.f);
  float q1 = fmaxf(__uint_as_float(zmx & 0xffff0000u), 0.f);
  float q2 = fmaxf(__uint_as_float(zmy << 16), 0.f);
  float q3 = fmaxf(__uint_as_float(zmy & 0xffff0000u), 0.f);

  const float* av_b = isHigh ? a_high : a_low;
  float4 ab = *(const float4*)&av_b[dbase];
  float4 am = *(const float4*)&a_mlp[dbase];
  float v1 = h0 * ab.x + h1 * ab.y + h2 * ab.z + h3 * ab.w;
  float v2 = isHigh ? 0.f : (q0 * am.x + q1 * am.y + q2 * am.z + q3 * am.w);
#pragma unroll
  for (int off = 1; off < 32; off <<= 1) {
    v1 += __shfl_xor(v1, off);
    v2 += __shfl_xor(v2, off);
  }
  float s_lo = __shfl(v1, 0);
  float s_hi = __shfl(v1, 32);
  float s_ml = __shfl(v2, 0);

  float g0 = 1.f / (1.f + __expf(-s_lo));
  float g1 = 1.f / (1.f + __expf(-s_hi));
  float g2 = 1.f / (1.f + __expf(-s_ml));
  const float inv3 = 1.f / 3.f;
  float m0 = (g0 * att_vec[0] + g1 * att_vec[3] + g2 * att_vec[6]) * inv3;
  float m1 = (g0 * att_vec[1] + g1 * att_vec[4] + g2 * att_vec[7]) * inv3;
  float m2 = (g0 * att_vec[2] + g1 * att_vec[5] + g2 * att_vec[8]) * inv3;
  float mx = fmaxf(m0, fmaxf(m1, m2));
  float e0 = __expf(m0 - mx), e1 = __expf(m1 - mx), e2 = __expf(m2 - mx);
  float inv = 1.f / (e0 + e1 + e2);
  float c0 = 3.f * inv * e0, c1 = 3.f * inv * e1, c2 = 3.f * inv * e2;

  float hh0 = __shfl_xor(h0, 32);
  float hh1 = __shfl_xor(h1, 32);
  float hh2 = __shfl_xor(h2, 32);
  float hh3 = __shfl_xor(h3, 32);

  if (!isHigh) {
    floatx4 o;
    o.x = c0 * h0 + c1 * hh0 + c2 * q0;
    o.y = c0 * h1 + c1 * hh1 + c2 * q1;
    o.z = c0 * h2 + c1 * hh2 + c2 * q2;
    o.w = c0 * h3 + c1 * hh3 + c2 * q3;
    __builtin_nontemporal_store(o,
                                (floatx4*)&out[(size_t)node * D_OUT + dbase]);
  }
}

// ---------------------------------------------------------------------------
extern "C" void kernel_launch(void* const* d_in, const int* in_sizes, int n_in,
                              void* d_out, int out_size, void* d_ws,
                              size_t ws_size, hipStream_t stream) {
  const float* x    = (const float*)d_in[0];
  const int*   esrc = (const int*)d_in[1];
  const int*   edst = (const int*)d_in[2];
  const float* wlo  = (const float*)d_in[3];
  const float* whi  = (const float*)d_in[4];
  const float* Wl   = (const float*)d_in[6];
  const float* Wh   = (const float*)d_in[7];
  const float* Wm   = (const float*)d_in[8];
  const float* alo  = (const float*)d_in[9];
  const float* ahi  = (const float*)d_in[10];
  const float* amlp = (const float*)d_in[11];
  const float* av   = (const float*)d_in[12];
  float* out = (float*)d_out;

  const int N = in_sizes[0] / D_IN;  // 100000
  const int E = in_sizes[1];         // 1600000
  const int NB1 = (N + 127) >> 7;    // coarse buckets (782)
  const int M = NB1 * NHB;           // bh entries (200192)

  char* ws = (char*)d_ws;
  size_t off = 0;
  auto carve = [&](size_t bytes) -> void* {
    void* p = ws + off;
    off = (off + bytes + 255) & ~(size_t)255;
    return p;
  };
  unsigned short* Zg     = (unsigned short*)carve((size_t)N * 256 * 2);
  unsigned short* Zm     = (unsigned short*)carve((size_t)N * 128 * 2);
  unsigned short* xb     = (unsigned short*)carve((size_t)N * D_IN * 2);
  unsigned short* Bpack  = (unsigned short*)carve(98304 * 2);
  int*   bh     = (int*)carve((size_t)M * 4);
  int*   bhscan = (int*)carve((size_t)M * 4);
  int*   bsum   = (int*)carve(256 * 4);
  int*   rowptr = (int*)carve((size_t)(N + 1) * 4);
  uint2* tmp    = (uint2*)carve((size_t)E * 8);
  uint2* meta   = (uint2*)carve((size_t)E * 8);

  int n8 = in_sizes[0] / 8;
  int nxb = (n8 + 255) / 256;

  // coarse histogram + prep (fused roles)
  hist_prep_kernel<<<NHB + 384 + nxb, 256, 0, stream>>>(Wl, Wh, Wm, Bpack, x,
                                                        xb, n8, edst, bh, E,
                                                        NB1);
  // exclusive scan of bh (scan3 folded into consumers)
  int nb1s = (M + 1023) / 1024;
  scan1_kernel<<<nb1s, 256, 0, stream>>>(bh, bhscan, bsum, M);
  scan2_kernel<<<1, 256, 0, stream>>>(bsum, nb1s);

  // fused gemm + coarse scatter (no global atomics)
  int ngemm = (N + 63) / 64;
  gemm_sort_kernel<<<ngemm + NHB, 512, 0, stream>>>(
      xb, Bpack, Zg, Zm, N, esrc, edst, wlo, whi, bhscan, bsum, tmp, E, NB1);

  // fine sort within buckets -> meta + rowptr
  fine_kernel<<<NB1, 256, 0, stream>>>(tmp, bhscan, bsum, meta, rowptr, NB1, N,
                                       E);

  node_kernel<<<(N + 1) / 2, 128, 0, stream>>>(
      Zg, Zm, rowptr, (const unsigned long long*)meta, alo, ahi, amlp, av, out,
      N);
}

// Round 14
// 395.842 us; speedup vs baseline: 1.4813x; 1.0564x over previous
//
#include <hip/hip_runtime.h>
#include <hip/hip_bf16.h>
#include <math.h>

#define D_IN   256
#define D_OUT  128
#define NHB    256   // coarse-sort blocks (hist + scatter replay partition)

typedef __attribute__((ext_vector_type(8))) short short8;
typedef __attribute__((ext_vector_type(4))) float floatx4;

__device__ __forceinline__ unsigned short f2bf(float f) {
  union { float f; unsigned u; } v; v.f = f;
  unsigned r = v.u + 0x7fffu + ((v.u >> 16) & 1u);  // RNE
  return (unsigned short)(r >> 16);
}

// ---------------------------------------------------------------------------
// FUSED coarse-histogram + repack. Two block roles (xcvt role DELETED —
// f32->bf16 now fused into gemm's coalesced A-staging):
//   bid < NHB   : LDS histogram of dst>>7 over this block's edge chunk
//                 -> bh[bucket*NHB + bid]   (no global atomics)
//   else        : repack [Wl|Wh|Wm] into MFMA B-fragment order
// ---------------------------------------------------------------------------
__global__ __launch_bounds__(256) void hist_prep_kernel(
    const float* __restrict__ Wl, const float* __restrict__ Wh,
    const float* __restrict__ Wm, unsigned short* __restrict__ Bpack,
    const int* __restrict__ dst, int* __restrict__ bh, int E, int NB1) {
  __shared__ int hist[1024];  // NB1 <= 1024 (N <= 131072)
  const int bid = blockIdx.x;
  const int t = threadIdx.x;
  if (bid < NHB) {
    for (int k = t; k < NB1; k += 256) hist[k] = 0;
    __syncthreads();
    const int chunk = (E + NHB - 1) / NHB;
    const int base = bid * chunk;
    const int lim = min(E, base + chunk);
    for (int e = base + t; e < lim; e += 256) atomicAdd(&hist[dst[e] >> 7], 1);
    __syncthreads();
    for (int k = t; k < NB1; k += 256) bh[k * NHB + bid] = hist[k];
  } else {
    // repack: frag f = kt*24+nt holds B[k=kt*32+quad*8+j][n=nt*16+(lane&15)]
    int tt = (bid - NHB) * 256 + t;  // 0..98303
    int j = tt & 7;
    int lane = (tt >> 3) & 63;
    int f = tt >> 9;  // 0..191
    int nt = f % 24, kt = f / 24;
    int k = kt * 32 + (lane >> 4) * 8 + j;
    int n_ = nt * 16 + (lane & 15);
    const float* W = (n_ < 128) ? Wl : (n_ < 256 ? Wh : Wm);
    Bpack[tt] = f2bf(W[k * D_OUT + (n_ & 127)]);
  }
}

// ---------------------------------------------------------------------------
// Exclusive scan over M = NB1*NHB ints. scan1 -> per-1024-chunk exclusive +
// chunk totals; scan2 -> exclusive scan of totals. Consumers read
// bhscan[i] + bsum[i>>10] directly (scan3 folded away).
// ---------------------------------------------------------------------------
__global__ __launch_bounds__(256) void scan1_kernel(
    const int* __restrict__ cnt, int* __restrict__ outp,
    int* __restrict__ bsum, int n) {
  __shared__ int sd[256];
  int t = threadIdx.x;
  int base = blockIdx.x * 1024 + t * 4;
  int v0 = base + 0 < n ? cnt[base + 0] : 0;
  int v1 = base + 1 < n ? cnt[base + 1] : 0;
  int v2 = base + 2 < n ? cnt[base + 2] : 0;
  int v3 = base + 3 < n ? cnt[base + 3] : 0;
  int tsum = v0 + v1 + v2 + v3;
  sd[t] = tsum;
  __syncthreads();
  for (int off = 1; off < 256; off <<= 1) {
    int add = (t >= off) ? sd[t - off] : 0;
    __syncthreads();
    sd[t] += add;
    __syncthreads();
  }
  int excl = sd[t] - tsum;
  if (base + 0 < n) outp[base + 0] = excl;
  if (base + 1 < n) outp[base + 1] = excl + v0;
  if (base + 2 < n) outp[base + 2] = excl + v0 + v1;
  if (base + 3 < n) outp[base + 3] = excl + v0 + v1 + v2;
  if (t == 255) bsum[blockIdx.x] = sd[255];
}

__global__ __launch_bounds__(256) void scan2_kernel(int* __restrict__ bsum,
                                                    int nb) {
  __shared__ int sd[256];
  int t = threadIdx.x;
  int v = t < nb ? bsum[t] : 0;
  sd[t] = v;
  __syncthreads();
  for (int off = 1; off < 256; off <<= 1) {
    int add = (t >= off) ? sd[t - off] : 0;
    __syncthreads();
    sd[t] += add;
    __syncthreads();
  }
  if (t < nb) bsum[t] = sd[t] - v;  // exclusive
}

// ---------------------------------------------------------------------------
// FUSED gemm + coarse scatter (even/odd role split, r6's proven pattern).
//   even ids < 2*NHB : replay edge chunk rb=bid>>1; positions from per-bucket
//                      LDS cursors seeded with bhscan[k*NHB+rb]+bsum fold
//                      -> tmp[pos] = {src | dlow7<<20, bf16(wl)|bf16(wh)<<16}
//   odd / remainder  : gemm tiles
// A staged through LDS (r12 win: coalesced linear span, XOR-swizzled chunks,
// K-loop at LDS latency). NEW (r14): A loads x directly as f32 and converts
// with v_cvt_pk_bf16_f32 (RNE, bit-identical to f2bf) during staging —
// deletes the xcvt pass + xb buffer (~150 MB of pipeline traffic). Staging
// stays fully coalesced (2x float4 per 16B bf16 chunk); gemm is latency-
// bound (1.4 TB/s, r11), so the extra bytes ride free.
// ---------------------------------------------------------------------------
#define LDSROW 392  // shorts/row for the epilogue tile: 784 B (16B-aligned)
__global__ __launch_bounds__(512, 4) void gemm_sort_kernel(
    const float* __restrict__ x,
    const unsigned short* __restrict__ Bpack, unsigned short* __restrict__ Zg,
    unsigned short* __restrict__ Zm, int n_nodes, const int* __restrict__ src,
    const int* __restrict__ dst, const float* __restrict__ wlo,
    const float* __restrict__ whi, const int* __restrict__ bhscan,
    const int* __restrict__ bsum, uint2* __restrict__ tmp, int E, int NB1) {
  __shared__ unsigned short lds[16384];  // 32 KB: A-tile, then epilogue tile
  const int bid = blockIdx.x;

  int gemm_id;
  if (bid < 2 * NHB) {
    if ((bid & 1) == 0) {  // ---- coarse scatter block ----
      int rb = bid >> 1;
      int* cur = (int*)lds;
      int t = threadIdx.x;
      for (int k = t; k < NB1; k += 512) {
        int idx = k * NHB + rb;
        cur[k] = bhscan[idx] + bsum[idx >> 10];
      }
      __syncthreads();
      const int chunk = (E + NHB - 1) / NHB;
      const int base = rb * chunk;
      const int lim = min(E, base + chunk);
      for (int e = base + t; e < lim; e += 512) {
        int d = dst[e];
        int pos = atomicAdd(&cur[d >> 7], 1);  // LDS atomic
        unsigned wl = f2bf(wlo[e]), wh = f2bf(whi[e]);
        tmp[pos] = make_uint2((unsigned)src[e] | ((unsigned)(d & 127) << 20),
                              wl | (wh << 16));
      }
      return;
    }
    gemm_id = bid >> 1;
  } else {
    gemm_id = bid - 2 * NHB + NHB;
  }

  // ---- gemm block ----
  const int lane = threadIdx.x & 63;
  const int w = threadIdx.x >> 6;  // 0..7: column group (3 ctiles)
  const int rowbase = gemm_id * 64;
  const int m16 = lane & 15, quad = lane >> 4;

  // cooperative A staging with fused f32->bf16: 64 rows x 256 floats.
  // bf16 chunk c (16B = 8 elems) of row -> loads 32B of x, cvt, store at
  // swizzled pc = (c&~7)|((c^row)&7).
  {
    const float4* xf = (const float4*)x;  // 64 float4 per row
#pragma unroll
    for (int i = 0; i < 4; i++) {
      int idx = i * 512 + threadIdx.x;  // 0..2047
      int row = idx >> 5, c = idx & 31;
      int gr = rowbase + row;
      if (gr > n_nodes - 1) gr = n_nodes - 1;  // clamp; stores are guarded
      float4 f0 = xf[(size_t)gr * 64 + c * 2];
      float4 f1 = xf[(size_t)gr * 64 + c * 2 + 1];
      unsigned w0, w1, w2, w3;
      asm("v_cvt_pk_bf16_f32 %0, %1, %2" : "=v"(w0) : "v"(f0.x), "v"(f0.y));
      asm("v_cvt_pk_bf16_f32 %0, %1, %2" : "=v"(w1) : "v"(f0.z), "v"(f0.w));
      asm("v_cvt_pk_bf16_f32 %0, %1, %2" : "=v"(w2) : "v"(f1.x), "v"(f1.y));
      asm("v_cvt_pk_bf16_f32 %0, %1, %2" : "=v"(w3) : "v"(f1.z), "v"(f1.w));
      union { uint4 u; short8 s8; } cv;
      cv.u = make_uint4(w0, w1, w2, w3);
      int pc = (c & ~7) | ((c ^ row) & 7);
      ((short8*)lds)[row * 32 + pc] = cv.s8;
    }
  }
  __syncthreads();

  floatx4 acc[4][3];
#pragma unroll
  for (int s = 0; s < 4; s++)
#pragma unroll
    for (int c = 0; c < 3; c++) acc[s][c] = (floatx4)(0.f);

  const short8* bp = (const short8*)Bpack + lane;

#pragma unroll
  for (int kt = 0; kt < 8; kt++) {
    short8 a[4];
#pragma unroll
    for (int s = 0; s < 4; s++) {
      int r_ = s * 16 + m16;
      int c_ = kt * 4 + quad;
      int pc = (c_ & ~7) | ((c_ ^ r_) & 7);
      a[s] = ((const short8*)lds)[r_ * 32 + pc];
    }
#pragma unroll
    for (int c = 0; c < 3; c++) {
      short8 b = bp[(kt * 24 + w * 3 + c) * 64];
#pragma unroll
      for (int s = 0; s < 4; s++)
        acc[s][c] =
            __builtin_amdgcn_mfma_f32_16x16x32_bf16(a[s], b, acc[s][c], 0, 0, 0);
    }
  }

  __syncthreads();  // all A-tile reads done before epilogue overwrites lds
  unsigned short* tile = lds;

  // two-pass LDS epilogue: strips {0,1} then {2,3} through a 32-row tile.
  // C-layout: local row = s*16+quad*4+r, col = (w*3+c)*16+m16.
  // chunk c8 0..31 -> Zg (512B gather row); 32..47 -> Zm plane.
#pragma unroll
  for (int half = 0; half < 2; half++) {
    if (half) __syncthreads();  // tile reuse: wait for pass-0 loads done
#pragma unroll
    for (int s = 0; s < 2; s++)
#pragma unroll
      for (int c = 0; c < 3; c++)
#pragma unroll
        for (int r = 0; r < 4; r++)
          tile[(s * 16 + quad * 4 + r) * LDSROW + (w * 3 + c) * 16 + m16] =
              f2bf(acc[half * 2 + s][c][r]);
    __syncthreads();
    // coalesced store: 32 rows x 48 chunks of 16B = 1536 chunks / 512 thr
#pragma unroll
    for (int it = 0; it < 3; it++) {
      int chunk = it * 512 + threadIdx.x;
      int row = chunk / 48, c8 = chunk % 48;
      int grow = rowbase + half * 32 + row;
      if (grow < n_nodes) {
        short8 v = *(const short8*)&tile[row * LDSROW + c8 * 8];
        if (c8 < 32)
          *(short8*)(Zg + (size_t)grow * 256 + c8 * 8) = v;
        else
          *(short8*)(Zm + (size_t)grow * 128 + (c8 - 32) * 8) = v;
      }
    }
  }
}

// ---------------------------------------------------------------------------
// Fine pass: one block per coarse bucket (128 nodes, ~2046 edges).
// LDS 128-bin histogram + LDS scan -> final meta grouped by dst + rowptr.
// ---------------------------------------------------------------------------
__global__ __launch_bounds__(256) void fine_kernel(
    const uint2* __restrict__ tmp, const int* __restrict__ bhscan,
    const int* __restrict__ bsum, uint2* __restrict__ meta,
    int* __restrict__ rowptr, int NB1, int n, int E) {
  __shared__ int fh[128];
  __shared__ int sd[128];
  __shared__ int cur[128];
  const int b = blockIdx.x;
  const int t = threadIdx.x;
  auto scanidx = [&](int i) { return bhscan[i] + bsum[i >> 10]; };
  const int s0 = scanidx(b * NHB);
  const int s1 = (b == NB1 - 1) ? E : scanidx((b + 1) * NHB);

  if (t < 128) fh[t] = 0;
  __syncthreads();
  for (int i = s0 + t; i < s1; i += 256)
    atomicAdd(&fh[(tmp[i].x >> 20) & 127], 1);
  __syncthreads();

  // exclusive scan of the 128 bins
  if (t < 128) sd[t] = fh[t];
  __syncthreads();
  for (int off = 1; off < 128; off <<= 1) {
    int add = (t >= off && t < 128) ? sd[t - off] : 0;
    __syncthreads();
    if (t < 128) sd[t] += add;
    __syncthreads();
  }
  if (t < 128) {
    int excl = sd[t] - fh[t];
    cur[t] = excl;
    int node = b * 128 + t;
    if (node < n) rowptr[node] = s0 + excl;
  }
  if (b == 0 && t == 0) rowptr[n] = E;
  __syncthreads();

  for (int i = s0 + t; i < s1; i += 256) {
    uint2 v = tmp[i];
    int d = (v.x >> 20) & 127;
    int pos = s0 + atomicAdd(&cur[d], 1);  // LDS atomic
    meta[pos] = make_uint2(v.x & 0xFFFFFu, v.y);
  }
}

// ---------------------------------------------------------------------------
// K_node: CSR gather + relu + attention3. 128-thr blocks = 2 independent
// waves = 2 nodes. Lane l<32: low dims 4l..4l+3; l>=32: high dims. One
// uint2 Zg load per edge (512B pow-2 rows), unroll x8; nontemporal streams.
// At ~3.9 TB/s effective on 400MB FETCH this is the random-gather fabric
// floor — declared done (r13).
// ---------------------------------------------------------------------------
__global__ __launch_bounds__(128) void node_kernel(
    const unsigned short* __restrict__ Zg, const unsigned short* __restrict__ Zm,
    const int* __restrict__ rowptr, const unsigned long long* __restrict__ meta,
    const float* __restrict__ a_low, const float* __restrict__ a_high,
    const float* __restrict__ a_mlp, const float* __restrict__ att_vec,
    float* __restrict__ out, int n_nodes) {
  int node = blockIdx.x * 2 + (threadIdx.x >> 6);
  if (node >= n_nodes) return;
  node = __builtin_amdgcn_readfirstlane(node);  // wave-uniform -> s_loads
  const int lane = threadIdx.x & 63;
  const int isHigh = lane >> 5;
  const int dbase = (lane & 31) * 4;
  const char* Zb = (const char*)Zg;

  const int start = rowptr[node];
  const int end = rowptr[node + 1];

  float acc0 = 0.f, acc1 = 0.f, acc2 = 0.f, acc3 = 0.f;
  auto wsel = [&](unsigned p) {
    return __uint_as_float(isHigh ? (p & 0xffff0000u) : (p << 16));
  };
  auto step = [&](uint2 z, float wv) {
    acc0 += wv * __uint_as_float(z.x << 16);
    acc1 += wv * __uint_as_float(z.x & 0xffff0000u);
    acc2 += wv * __uint_as_float(z.y << 16);
    acc3 += wv * __uint_as_float(z.y & 0xffff0000u);
  };

  int j = start;
  const int nfull = (end - start) & ~7;
  for (; j < start + nfull; j += 8) {
    unsigned long long m[8];
    uint2 z[8];
#pragma unroll
    for (int u = 0; u < 8; u++) m[u] = __builtin_nontemporal_load(&meta[j + u]);
#pragma unroll
    for (int u = 0; u < 8; u++)
      z[u] = *(const uint2*)(Zb + ((size_t)(unsigned)m[u]) * 512 + lane * 8);
#pragma unroll
    for (int u = 0; u < 8; u++) step(z[u], wsel((unsigned)(m[u] >> 32)));
  }
  for (; j < end; j++) {
    unsigned long long m0 = __builtin_nontemporal_load(&meta[j]);
    uint2 z0 = *(const uint2*)(Zb + ((size_t)(unsigned)m0) * 512 + lane * 8);
    step(z0, wsel((unsigned)(m0 >> 32)));
  }

  float h0 = fmaxf(acc0, 0.f), h1 = fmaxf(acc1, 0.f);
  float h2 = fmaxf(acc2, 0.f), h3 = fmaxf(acc3, 0.f);

  unsigned long long zmq = __builtin_nontemporal_load(
      (const unsigned long long*)((const char*)Zm + (size_t)node * 256 +
                                  (size_t)(lane & 31) * 8));
  unsigned zmx = (unsigned)zmq, zmy = (unsigned)(zmq >> 32);
  float q0 = fmaxf(__uint_as_float(zmx << 16), 0.f);
  float q1 = fmaxf(__uint_as_float(zmx & 0xffff0000u), 0.f);
  float q2 = fmaxf(__uint_as_float(zmy << 16), 0.f);
  float q3 = fmaxf(__uint_as_float(zmy & 0xffff0000u), 0.f);

  const float* av_b = isHigh ? a_high : a_low;
  float4 ab = *(const float4*)&av_b[dbase];
  float4 am = *(const float4*)&a_mlp[dbase];
  float v1 = h0 * ab.x + h1 * ab.y + h2 * ab.z + h3 * ab.w;
  float v2 = isHigh ? 0.f : (q0 * am.x + q1 * am.y + q2 * am.z + q3 * am.w);
#pragma unroll
  for (int off = 1; off < 32; off <<= 1) {
    v1 += __shfl_xor(v1, off);
    v2 += __shfl_xor(v2, off);
  }
  float s_lo = __shfl(v1, 0);
  float s_hi = __shfl(v1, 32);
  float s_ml = __shfl(v2, 0);

  float g0 = 1.f / (1.f + __expf(-s_lo));
  float g1 = 1.f / (1.f + __expf(-s_hi));
  float g2 = 1.f / (1.f + __expf(-s_ml));
  const float inv3 = 1.f / 3.f;
  float m0 = (g0 * att_vec[0] + g1 * att_vec[3] + g2 * att_vec[6]) * inv3;
  float m1 = (g0 * att_vec[1] + g1 * att_vec[4] + g2 * att_vec[7]) * inv3;
  float m2 = (g0 * att_vec[2] + g1 * att_vec[5] + g2 * att_vec[8]) * inv3;
  float mx = fmaxf(m0, fmaxf(m1, m2));
  float e0 = __expf(m0 - mx), e1 = __expf(m1 - mx), e2 = __expf(m2 - mx);
  float inv = 1.f / (e0 + e1 + e2);
  float c0 = 3.f * inv * e0, c1 = 3.f * inv * e1, c2 = 3.f * inv * e2;

  float hh0 = __shfl_xor(h0, 32);
  float hh1 = __shfl_xor(h1, 32);
  float hh2 = __shfl_xor(h2, 32);
  float hh3 = __shfl_xor(h3, 32);

  if (!isHigh) {
    floatx4 o;
    o.x = c0 * h0 + c1 * hh0 + c2 * q0;
    o.y = c0 * h1 + c1 * hh1 + c2 * q1;
    o.z = c0 * h2 + c1 * hh2 + c2 * q2;
    o.w = c0 * h3 + c1 * hh3 + c2 * q3;
    __builtin_nontemporal_store(o,
                                (floatx4*)&out[(size_t)node * D_OUT + dbase]);
  }
}

// ---------------------------------------------------------------------------
extern "C" void kernel_launch(void* const* d_in, const int* in_sizes, int n_in,
                              void* d_out, int out_size, void* d_ws,
                              size_t ws_size, hipStream_t stream) {
  const float* x    = (const float*)d_in[0];
  const int*   esrc = (const int*)d_in[1];
  const int*   edst = (const int*)d_in[2];
  const float* wlo  = (const float*)d_in[3];
  const float* whi  = (const float*)d_in[4];
  const float* Wl   = (const float*)d_in[6];
  const float* Wh   = (const float*)d_in[7];
  const float* Wm   = (const float*)d_in[8];
  const float* alo  = (const float*)d_in[9];
  const float* ahi  = (const float*)d_in[10];
  const float* amlp = (const float*)d_in[11];
  const float* av   = (const float*)d_in[12];
  float* out = (float*)d_out;

  const int N = in_sizes[0] / D_IN;  // 100000
  const int E = in_sizes[1];         // 1600000
  const int NB1 = (N + 127) >> 7;    // coarse buckets (782)
  const int M = NB1 * NHB;           // bh entries (200192)

  char* ws = (char*)d_ws;
  size_t off = 0;
  auto carve = [&](size_t bytes) -> void* {
    void* p = ws + off;
    off = (off + bytes + 255) & ~(size_t)255;
    return p;
  };
  unsigned short* Zg     = (unsigned short*)carve((size_t)N * 256 * 2);
  unsigned short* Zm     = (unsigned short*)carve((size_t)N * 128 * 2);
  unsigned short* Bpack  = (unsigned short*)carve(98304 * 2);
  int*   bh     = (int*)carve((size_t)M * 4);
  int*   bhscan = (int*)carve((size_t)M * 4);
  int*   bsum   = (int*)carve(256 * 4);
  int*   rowptr = (int*)carve((size_t)(N + 1) * 4);
  uint2* tmp    = (uint2*)carve((size_t)E * 8);
  uint2* meta   = (uint2*)carve((size_t)E * 8);

  // coarse histogram + repack (fused roles; xcvt deleted)
  hist_prep_kernel<<<NHB + 384, 256, 0, stream>>>(Wl, Wh, Wm, Bpack, edst, bh,
                                                  E, NB1);
  // exclusive scan of bh (scan3 folded into consumers)
  int nb1s = (M + 1023) / 1024;
  scan1_kernel<<<nb1s, 256, 0, stream>>>(bh, bhscan, bsum, M);
  scan2_kernel<<<1, 256, 0, stream>>>(bsum, nb1s);

  // fused gemm (f32 A, in-staging cvt) + coarse scatter (no global atomics)
  int ngemm = (N + 63) / 64;
  gemm_sort_kernel<<<ngemm + NHB, 512, 0, stream>>>(
      x, Bpack, Zg, Zm, N, esrc, edst, wlo, whi, bhscan, bsum, tmp, E, NB1);

  // fine sort within buckets -> meta + rowptr
  fine_kernel<<<NB1, 256, 0, stream>>>(tmp, bhscan, bsum, meta, rowptr, NB1, N,
                                       E);

  node_kernel<<<(N + 1) / 2, 128, 0, stream>>>(
      Zg, Zm, rowptr, (const unsigned long long*)meta, alo, ahi, amlp, av, out,
      N);
}